// Round 6
// baseline (323.661 us; speedup 1.0000x reference)
//
#include <hip/hip_runtime.h>

typedef _Float16 v8h __attribute__((ext_vector_type(8)));
typedef _Float16 v4h __attribute__((ext_vector_type(4)));
typedef float v4f __attribute__((ext_vector_type(4)));
#define HF _Float16

// dims
#define Bn 8
#define Cc 512
#define CI 256
#define HW 4096   // 64*64
#define Mp 1024   // 32*32 pooled

__device__ __forceinline__ void gload16(const void* g, void* l) {
    __builtin_amdgcn_global_load_lds((const __attribute__((address_space(1))) void*)g,
                                     (__attribute__((address_space(3))) void*)l, 16, 0, 0);
}

// ---------------- prep: weights fp32->f16, BN fold ----------------
__global__ __launch_bounds__(256) void prep_kernel(
    const float* __restrict__ w_g, const float* __restrict__ b_g,
    const float* __restrict__ w_th, const float* __restrict__ b_th,
    const float* __restrict__ w_ph, const float* __restrict__ b_ph,
    const float* __restrict__ w_out, const float* __restrict__ b_out,
    const float* __restrict__ gamma, const float* __restrict__ beta,
    const float* __restrict__ mean, const float* __restrict__ var,
    HF* __restrict__ wall, float* __restrict__ ball,
    HF* __restrict__ wo, float* __restrict__ scale, float* __restrict__ shift)
{
    int idx = blockIdx.x * 256 + threadIdx.x;
    if (idx < 768*512) {
        int o = idx >> 9;
        float v = (o < 256) ? w_th[idx] : (o < 512) ? w_ph[idx - 256*512] : w_g[idx - 512*512];
        wall[idx] = (HF)v;
    }
    if (idx < 512*256) wo[idx] = (HF)w_out[idx];
    if (idx < 768) ball[idx] = (idx < 256) ? b_th[idx] : (idx < 512) ? b_ph[idx-256] : b_g[idx-512];
    if (idx < 512) {
        float inv = gamma[idx] * rsqrtf(var[idx] + 1e-5f);
        scale[idx] = inv;
        shift[idx] = (b_out[idx] - mean[idx]) * inv + beta[idx];
    }
}

// ---------------- transpose x: (b,c,s) fp32 -> xT (b,s,c) f16 ----------------
__global__ __launch_bounds__(256) void transpose_x_kernel(const float* __restrict__ x, HF* __restrict__ xT)
{
    __shared__ float tile[64][65];
    int b = blockIdx.z;
    int c0 = blockIdx.y * 64, s0 = blockIdx.x * 64;
    int tr = threadIdx.x >> 6, ts = threadIdx.x & 63;
    #pragma unroll
    for (int i = 0; i < 16; ++i) {
        int r = tr + i*4;
        tile[r][ts] = x[((long)(b*Cc) + c0 + r)*HW + s0 + ts];
    }
    __syncthreads();
    #pragma unroll
    for (int i = 0; i < 16; ++i) {
        int r = tr + i*4;
        xT[((long)b*HW + s0 + r)*Cc + c0 + ts] = (HF)tile[ts][r];
    }
}

// ---------------- 2x2 maxpool from s-major phi: Ph[s, c] -> Pt[m, c] ----------------
// Ph = TP + col offset 256, row stride 512. Coalesced v8h reads/writes.
__global__ __launch_bounds__(256) void pool_sm_kernel(const HF* __restrict__ TP, HF* __restrict__ Pt)
{
    int idx = blockIdx.x * 256 + threadIdx.x;   // Bn*1024*32
    int c8 = idx & 31;
    int m  = (idx >> 5) & 1023;
    int b  = idx >> 15;
    int h2 = m >> 5, w2 = m & 31;
    int s00 = h2*128 + w2*2;
    const HF* base = TP + ((long)b*HW + s00)*512 + 256 + c8*8;
    v8h a0 = *(const v8h*)(base);
    v8h a1 = *(const v8h*)(base + 512);
    v8h a2 = *(const v8h*)(base + 64*512);
    v8h a3 = *(const v8h*)(base + 65*512);
    v8h o;
    #pragma unroll
    for (int j = 0; j < 8; ++j) {
        float v = fmaxf(fmaxf((float)a0[j], (float)a1[j]), fmaxf((float)a2[j], (float)a3[j]));
        o[j] = (HF)v;
    }
    *(v8h*)(Pt + ((long)b*Mp + m)*CI + c8*8) = o;
}

// ---------------- 2x2 maxpool c-major: Gg (b,c,64,64) -> G (b,c,32,32) ----------------
__global__ __launch_bounds__(256) void pool_kernel(const HF* __restrict__ src, long sSrc,
                                                   HF* __restrict__ dst, long sDst)
{
    long idx = (long)blockIdx.x * 256 + threadIdx.x;   // Bn*256*1024
    int m = idx & 1023;
    long bc = idx >> 10;
    int c = (int)(bc & 255);
    int b = (int)(bc >> 8);
    int h2 = m >> 5, w2 = m & 31;
    const HF* p = src + (long)b*sSrc + (long)c*HW + h2*128 + w2*2;
    float v = fmaxf(fmaxf((float)p[0], (float)p[1]), fmaxf((float)p[64], (float)p[65]));
    dst[(long)b*sDst + (long)c*Mp + m] = (HF)v;
}

// ---------------- generic tiled gemm_bt: C[i,j] = sum_k A[i,k]*B[j,k] ----------------
// gload_lds staged, double-buffered, LDS [kg][128][8] k-group-major (conflict-free).
// EPI 0: f16 = acc + rowBias[i];  EPI 2: f32 = acc*scale[i]+shift[i]+X;  EPI 3: f16 = acc + colBias[j]
template<int EPI>
__global__ __launch_bounds__(256) void gemm_bt_kernel(
    const HF* __restrict__ A, long sA, const HF* __restrict__ B, long sB,
    void* __restrict__ Cv, long sC, int M, int N, int K,
    const float* __restrict__ bias,
    const float* __restrict__ rowScale, const float* __restrict__ rowShift,
    const float* __restrict__ Xres, long sX)
{
    __shared__ alignas(16) HF As[2][4096];   // [4 kg][128 row][8]
    __shared__ alignas(16) HF Bs[2][4096];
    int b = blockIdx.z;
    int i0 = blockIdx.y * 128;
    int j0 = blockIdx.x * 128;
    const HF* Ab = A + (long)b * sA;
    const HF* Bb = B + (long)b * sB;
    int tid = threadIdx.x;
    int lane = tid & 63, w = tid >> 6;
    int wr = w >> 1, wc = w & 1;
    int lr = lane & 15, lkg = lane >> 4;

    auto stage = [&](int bsel, int k0) {
        #pragma unroll
        for (int q = 0; q < 2; ++q) {
            int idx = q*256 + tid;           // 0..511; dest = idx*16B, kg wave-uniform
            int kg = idx >> 7, row = idx & 127;
            gload16(Ab + (long)(i0+row)*K + k0 + kg*8, As[bsel] + (size_t)idx*8);
            gload16(Bb + (long)(j0+row)*K + k0 + kg*8, Bs[bsel] + (size_t)idx*8);
        }
    };

    v4f acc[4][4];
    #pragma unroll
    for (int i = 0; i < 4; ++i)
        #pragma unroll
        for (int j = 0; j < 4; ++j) { v4f z = {0.f,0.f,0.f,0.f}; acc[i][j] = z; }

    stage(0, 0);
    __syncthreads();
    int cur = 0;
    for (int k0 = 0; k0 < K; k0 += 32) {
        if (k0 + 32 < K) stage(cur ^ 1, k0 + 32);
        v8h af[4], bfr[4];
        #pragma unroll
        for (int mf = 0; mf < 4; ++mf)
            af[mf] = *(const v8h*)(As[cur] + lkg*1024 + (wr*64 + mf*16 + lr)*8);
        #pragma unroll
        for (int nf = 0; nf < 4; ++nf)
            bfr[nf] = *(const v8h*)(Bs[cur] + lkg*1024 + (wc*64 + nf*16 + lr)*8);
        __builtin_amdgcn_s_setprio(1);
        #pragma unroll
        for (int mf = 0; mf < 4; ++mf)
            #pragma unroll
            for (int nf = 0; nf < 4; ++nf)
                acc[mf][nf] = __builtin_amdgcn_mfma_f32_16x16x32_f16(af[mf], bfr[nf], acc[mf][nf], 0, 0, 0);
        __builtin_amdgcn_s_setprio(0);
        __syncthreads();
        cur ^= 1;
    }

    int rbase = (lane >> 4) * 4;
    #pragma unroll
    for (int mf = 0; mf < 4; ++mf) {
        #pragma unroll
        for (int nf = 0; nf < 4; ++nf) {
            #pragma unroll
            for (int r = 0; r < 4; ++r) {
                int row = i0 + wr*64 + mf*16 + rbase + r;
                int col = j0 + wc*64 + nf*16 + lr;
                float v = acc[mf][nf][r];
                if (EPI == 0) {
                    v += bias[row];
                    ((HF*)Cv + (long)b*sC)[(long)row*N + col] = (HF)v;
                } else if (EPI == 3) {
                    v += bias[col];
                    ((HF*)Cv + (long)b*sC)[(long)row*N + col] = (HF)v;
                } else {
                    float* Cf = (float*)Cv + (long)b*sC;
                    const float* Xb = Xres + (long)b*sX;
                    long o = (long)row*N + col;
                    Cf[o] = v * rowScale[row] + rowShift[row] + Xb[o];
                }
            }
        }
    }
}

// ---------------- fused flash attention v5 ----------------
// grid 256 linear (batch = bid&7 -> XCD-pinned), 4 waves x 32 rows = 128 rows/block.
// P staged in LDS (double-buffered gload_lds, k-group-major, conflict-free);
// G fragments read DIRECT from global (L2-resident per XCD) on the VMEM pipe.
// Online softmax: max butterfly, conditional rescale, per-lane sums.
__global__ __launch_bounds__(256) void fused_attn_kernel(
    const HF* __restrict__ TP,   // [B][4096][512], theta = cols 0..255
    const HF* __restrict__ Pt,   // [B][1024][256]
    const HF* __restrict__ G,    // [B][256][1024]
    HF* __restrict__ Yt)         // [B][4096][256]
{
    __shared__ alignas(16) HF P_lds[2][8192];   // [32 kg][32 row][8]
    __shared__ alignas(16) HF P_buf[4][32][36]; // padded stride 72B (0-conflict measured)

    int bid = blockIdx.x;
    int b = bid & 7;
    int ntile = bid >> 3;
    int tid = threadIdx.x;
    int lane = tid & 63, w = tid >> 6;
    int lr = lane & 15, lkg = lane >> 4;
    int nbase = ntile * 128 + w * 32;

    const HF* Tq = TP + ((long)b*HW + nbase) * 512;
    const HF* Pb = Pt + (long)b*Mp*CI;
    const HF* Gb = G  + (long)b*CI*Mp;

    auto stage = [&](int bsel, int m0) {
        #pragma unroll
        for (int q = 0; q < 4; ++q) {
            int idxp = (w*4 + q)*64 + lane;         // 0..1023; dest = idxp*16B
            int pkg = idxp >> 5, prow = idxp & 31;  // [32 kg][32 row][8]
            gload16(Pb + (long)(m0 + prow)*CI + pkg*8, P_lds[bsel] + (size_t)idxp*8);
        }
    };

    // Q fragments: 2 row-tiles x 8 k-frags, registers for whole kernel
    v8h af[2][8];
    #pragma unroll
    for (int rt = 0; rt < 2; ++rt)
        #pragma unroll
        for (int kf = 0; kf < 8; ++kf)
            af[rt][kf] = *(const v8h*)(Tq + (long)(rt*16 + lr)*512 + kf*32 + lkg*8);

    v4f acc_y[2][16];
    #pragma unroll
    for (int rt = 0; rt < 2; ++rt)
        #pragma unroll
        for (int i = 0; i < 16; ++i) { v4f z = {0.f,0.f,0.f,0.f}; acc_y[rt][i] = z; }
    float mrun[2][4] = {{-1e30f,-1e30f,-1e30f,-1e30f},{-1e30f,-1e30f,-1e30f,-1e30f}};
    float lsum[2][4] = {{0.f,0.f,0.f,0.f},{0.f,0.f,0.f,0.f}};

    stage(0, 0);
    __syncthreads();

    int cur = 0;
    for (int t = 0; t < 32; ++t) {
        if (t < 31) stage(cur ^ 1, (t+1)*32);

        // QK^T: S[32 n][32 m]
        v4f acc[2][2];
        #pragma unroll
        for (int rt = 0; rt < 2; ++rt)
            #pragma unroll
            for (int nf = 0; nf < 2; ++nf) { v4f z = {0.f,0.f,0.f,0.f}; acc[rt][nf] = z; }
        #pragma unroll
        for (int kf = 0; kf < 8; ++kf) {
            #pragma unroll
            for (int nf = 0; nf < 2; ++nf) {
                v8h bfr = *(const v8h*)(P_lds[cur] + (kf*4 + lkg)*256 + (nf*16 + lr)*8);
                acc[0][nf] = __builtin_amdgcn_mfma_f32_16x16x32_f16(af[0][kf], bfr, acc[0][nf], 0, 0, 0);
                acc[1][nf] = __builtin_amdgcn_mfma_f32_16x16x32_f16(af[1][kf], bfr, acc[1][nf], 0, 0, 0);
            }
        }

        // online softmax per row-tile
        #pragma unroll
        for (int rt = 0; rt < 2; ++rt) {
            #pragma unroll
            for (int r = 0; r < 4; ++r) {
                float cm = fmaxf(acc[rt][0][r], acc[rt][1][r]);
                #pragma unroll
                for (int d = 1; d < 16; d <<= 1) cm = fmaxf(cm, __shfl_xor(cm, d));
                if (cm > mrun[rt][r]) {
                    float alpha = __expf(mrun[rt][r] - cm);
                    mrun[rt][r] = cm;
                    lsum[rt][r] *= alpha;
                    #pragma unroll
                    for (int cf = 0; cf < 16; ++cf) acc_y[rt][cf][r] *= alpha;
                }
                int row = rt*16 + lkg*4 + r;
                #pragma unroll
                for (int nf = 0; nf < 2; ++nf) {
                    float p = __expf(acc[rt][nf][r] - mrun[rt][r]);   // <= 1
                    lsum[rt][r] += p;
                    P_buf[w][row][nf*16 + lr] = (HF)p;
                }
            }
        }

        // PV: Y[32 n][256 c] += P(32x32) @ G_chunk^T, G direct from global (L2)
        v8h ap0, ap1;
        {
            v4h a0 = *(const v4h*)(&P_buf[w][lr][lkg*8]);
            v4h a1 = *(const v4h*)(&P_buf[w][lr][lkg*8 + 4]);
            ap0 = __builtin_shufflevector(a0, a1, 0,1,2,3,4,5,6,7);
            v4h b0 = *(const v4h*)(&P_buf[w][16 + lr][lkg*8]);
            v4h b1 = *(const v4h*)(&P_buf[w][16 + lr][lkg*8 + 4]);
            ap1 = __builtin_shufflevector(b0, b1, 0,1,2,3,4,5,6,7);
        }
        const HF* gptr = Gb + (long)lr*Mp + t*32 + lkg*8;
        #pragma unroll
        for (int cf = 0; cf < 16; ++cf) {
            v8h bg = *(const v8h*)(gptr + (long)cf*16*Mp);
            acc_y[0][cf] = __builtin_amdgcn_mfma_f32_16x16x32_f16(ap0, bg, acc_y[0][cf], 0, 0, 0);
            acc_y[1][cf] = __builtin_amdgcn_mfma_f32_16x16x32_f16(ap1, bg, acc_y[1][cf], 0, 0, 0);
        }

        __syncthreads();   // drains gload_lds for cur^1; all waves done reading cur
        cur ^= 1;
    }

    // epilogue: cross-lane sum reduce, Y /= l, write f16
    HF* Yb = Yt + ((long)b*HW + nbase) * CI;
    #pragma unroll
    for (int rt = 0; rt < 2; ++rt) {
        #pragma unroll
        for (int r = 0; r < 4; ++r) {
            float s = lsum[rt][r];
            #pragma unroll
            for (int d = 1; d < 16; d <<= 1) s += __shfl_xor(s, d);
            float inv = 1.f / s;
            #pragma unroll
            for (int cf = 0; cf < 16; ++cf)
                Yb[(long)(rt*16 + lkg*4 + r)*CI + cf*16 + lr] = (HF)(acc_y[rt][cf][r] * inv);
        }
    }
}

extern "C" void kernel_launch(void* const* d_in, const int* in_sizes, int n_in,
                              void* d_out, int out_size, void* d_ws, size_t ws_size,
                              hipStream_t stream)
{
    const float* x     = (const float*)d_in[0];
    const float* w_g   = (const float*)d_in[1];
    const float* b_g   = (const float*)d_in[2];
    const float* w_th  = (const float*)d_in[3];
    const float* b_th  = (const float*)d_in[4];
    const float* w_ph  = (const float*)d_in[5];
    const float* b_ph  = (const float*)d_in[6];
    const float* w_out = (const float*)d_in[7];
    const float* b_out = (const float*)d_in[8];
    const float* gamma = (const float*)d_in[9];
    const float* beta  = (const float*)d_in[10];
    const float* mean  = (const float*)d_in[11];
    const float* var   = (const float*)d_in[12];
    float* out = (float*)d_out;

    char* ws = (char*)d_ws;
    size_t off = 0;
    auto alloc = [&](size_t bytes) { void* p = ws + off; off += (bytes + 255) & ~(size_t)255; return p; };
    HF*    wall  = (HF*)alloc((size_t)768*512*2);   // rows: theta 0-255, phi 256-511, g 512-767
    float* ball  = (float*)alloc(768*4);
    HF*    wo    = (HF*)alloc((size_t)512*256*2);
    float* scale = (float*)alloc(512*4);
    float* shift = (float*)alloc(512*4);
    HF*    xT    = (HF*)alloc((size_t)Bn*HW*Cc*2);
    HF*    TP    = (HF*)alloc((size_t)Bn*HW*512*2);  // [s][theta|phi]
    HF*    Gg    = (HF*)alloc((size_t)Bn*CI*HW*2);   // g conv, c-major
    HF*    Pt    = (HF*)alloc((size_t)Bn*Mp*CI*2);
    HF*    G     = (HF*)alloc((size_t)Bn*CI*Mp*2);
    HF*    Yt    = (HF*)alloc((size_t)Bn*HW*CI*2);

    prep_kernel<<<1536, 256, 0, stream>>>(w_g,b_g,w_th,b_th,w_ph,b_ph,w_out,b_out,gamma,beta,mean,var,
                                          wall, ball, wo, scale, shift);
    transpose_x_kernel<<<dim3(64,8,Bn), 256, 0, stream>>>(x, xT);
    // TP[b, s, o] = xT @ {w_th|w_ph}^T + colBias  (theta+phi, s-major: no transpose needed)
    gemm_bt_kernel<3><<<dim3(4,32,Bn), 256, 0, stream>>>(xT, (long)HW*Cc, wall, 0, TP, (long)HW*512,
                                                         HW, 512, Cc, ball, nullptr, nullptr, nullptr, 0);
    // Gg[b, c, s] = w_g @ xT^T + rowBias  (c-major for PV's G[c][m] layout)
    gemm_bt_kernel<0><<<dim3(32,2,Bn), 256, 0, stream>>>(wall + (size_t)512*512, 0, xT, (long)HW*Cc,
                                                         Gg, (long)CI*HW, CI, HW, Cc, ball + 512,
                                                         nullptr, nullptr, nullptr, 0);
    // phi -> pooled Pt[b, m, c] straight from TP
    pool_sm_kernel<<<1024, 256, 0, stream>>>(TP, Pt);
    // g -> pooled G[b, c, m]
    pool_kernel<<<8192, 256, 0, stream>>>(Gg, (long)CI*HW, G, (long)CI*Mp);
    // fused scores+softmax+PV -> Yt[b, n, c]
    fused_attn_kernel<<<256, 256, 0, stream>>>(TP, Pt, G, Yt);
    // out[b, co, n] = wo @ Yt^T * scale + shift + x
    gemm_bt_kernel<2><<<dim3(32,4,Bn), 256, 0, stream>>>(wo, 0, Yt, (long)HW*CI, out, (long)Cc*HW,
                                                         Cc, HW, CI, nullptr, scale, shift, x, (long)Cc*HW);
}

// Round 7
// 302.607 us; speedup vs baseline: 1.0696x; 1.0696x over previous
//
#include <hip/hip_runtime.h>

typedef _Float16 v8h __attribute__((ext_vector_type(8)));
typedef _Float16 v4h __attribute__((ext_vector_type(4)));
typedef float v4f __attribute__((ext_vector_type(4)));
#define HF _Float16

// dims
#define Bn 8
#define Cc 512
#define CI 256
#define HW 4096   // 64*64
#define Mp 1024   // 32*32 pooled

__device__ __forceinline__ void gload16(const void* g, void* l) {
    __builtin_amdgcn_global_load_lds((const __attribute__((address_space(1))) void*)g,
                                     (__attribute__((address_space(3))) void*)l, 16, 0, 0);
}

// ---------------- prep: weights fp32->f16, BN fold ----------------
__global__ __launch_bounds__(256) void prep_kernel(
    const float* __restrict__ w_g, const float* __restrict__ b_g,
    const float* __restrict__ w_th, const float* __restrict__ b_th,
    const float* __restrict__ w_ph, const float* __restrict__ b_ph,
    const float* __restrict__ w_out, const float* __restrict__ b_out,
    const float* __restrict__ gamma, const float* __restrict__ beta,
    const float* __restrict__ mean, const float* __restrict__ var,
    HF* __restrict__ wall, float* __restrict__ ball,
    HF* __restrict__ wo, float* __restrict__ scale, float* __restrict__ shift)
{
    int idx = blockIdx.x * 256 + threadIdx.x;
    if (idx < 768*512) {
        int o = idx >> 9;
        float v = (o < 256) ? w_th[idx] : (o < 512) ? w_ph[idx - 256*512] : w_g[idx - 512*512];
        wall[idx] = (HF)v;
    }
    if (idx < 512*256) wo[idx] = (HF)w_out[idx];
    if (idx < 768) ball[idx] = (idx < 256) ? b_th[idx] : (idx < 512) ? b_ph[idx-256] : b_g[idx-512];
    if (idx < 512) {
        float inv = gamma[idx] * rsqrtf(var[idx] + 1e-5f);
        scale[idx] = inv;
        shift[idx] = (b_out[idx] - mean[idx]) * inv + beta[idx];
    }
}

// ---------------- transpose x: (b,c,s) fp32 -> xT (b,s,c) f16 ----------------
__global__ __launch_bounds__(256) void transpose_x_kernel(const float* __restrict__ x, HF* __restrict__ xT)
{
    __shared__ float tile[64][65];
    int b = blockIdx.z;
    int c0 = blockIdx.y * 64, s0 = blockIdx.x * 64;
    int tr = threadIdx.x >> 6, ts = threadIdx.x & 63;
    #pragma unroll
    for (int i = 0; i < 16; ++i) {
        int r = tr + i*4;
        tile[r][ts] = x[((long)(b*Cc) + c0 + r)*HW + s0 + ts];
    }
    __syncthreads();
    #pragma unroll
    for (int i = 0; i < 16; ++i) {
        int r = tr + i*4;
        xT[((long)b*HW + s0 + r)*Cc + c0 + ts] = (HF)tile[ts][r];
    }
}

// ---------------- 2x2 maxpool from s-major phi: Ph[s, c] -> Pt[m, c] ----------------
__global__ __launch_bounds__(256) void pool_sm_kernel(const HF* __restrict__ TP, HF* __restrict__ Pt)
{
    int idx = blockIdx.x * 256 + threadIdx.x;   // Bn*1024*32
    int c8 = idx & 31;
    int m  = (idx >> 5) & 1023;
    int b  = idx >> 15;
    int h2 = m >> 5, w2 = m & 31;
    int s00 = h2*128 + w2*2;
    const HF* base = TP + ((long)b*HW + s00)*512 + 256 + c8*8;
    v8h a0 = *(const v8h*)(base);
    v8h a1 = *(const v8h*)(base + 512);
    v8h a2 = *(const v8h*)(base + 64*512);
    v8h a3 = *(const v8h*)(base + 65*512);
    v8h o;
    #pragma unroll
    for (int j = 0; j < 8; ++j) {
        float v = fmaxf(fmaxf((float)a0[j], (float)a1[j]), fmaxf((float)a2[j], (float)a3[j]));
        o[j] = (HF)v;
    }
    *(v8h*)(Pt + ((long)b*Mp + m)*CI + c8*8) = o;
}

// ---------------- 2x2 maxpool c-major: Gg (b,c,64,64) -> G (b,c,32,32) ----------------
__global__ __launch_bounds__(256) void pool_kernel(const HF* __restrict__ src, long sSrc,
                                                   HF* __restrict__ dst, long sDst)
{
    long idx = (long)blockIdx.x * 256 + threadIdx.x;   // Bn*256*1024
    int m = idx & 1023;
    long bc = idx >> 10;
    int c = (int)(bc & 255);
    int b = (int)(bc >> 8);
    int h2 = m >> 5, w2 = m & 31;
    const HF* p = src + (long)b*sSrc + (long)c*HW + h2*128 + w2*2;
    float v = fmaxf(fmaxf((float)p[0], (float)p[1]), fmaxf((float)p[64], (float)p[65]));
    dst[(long)b*sDst + (long)c*Mp + m] = (HF)v;
}

// ---------------- generic tiled gemm_bt: C[i,j] = sum_k A[i,k]*B[j,k] ----------------
// gload_lds staged, double-buffered, LDS [kg][128][8] k-group-major (conflict-free).
// EPI 0: f16 = acc + rowBias[i];  EPI 2: f32 = acc*scale[i]+shift[i]+X;  EPI 3: f16 = acc + colBias[j]
template<int EPI>
__global__ __launch_bounds__(256) void gemm_bt_kernel(
    const HF* __restrict__ A, long sA, const HF* __restrict__ B, long sB,
    void* __restrict__ Cv, long sC, int M, int N, int K,
    const float* __restrict__ bias,
    const float* __restrict__ rowScale, const float* __restrict__ rowShift,
    const float* __restrict__ Xres, long sX)
{
    __shared__ alignas(16) HF As[2][4096];   // [4 kg][128 row][8]
    __shared__ alignas(16) HF Bs[2][4096];
    int b = blockIdx.z;
    int i0 = blockIdx.y * 128;
    int j0 = blockIdx.x * 128;
    const HF* Ab = A + (long)b * sA;
    const HF* Bb = B + (long)b * sB;
    int tid = threadIdx.x;
    int lane = tid & 63, w = tid >> 6;
    int wr = w >> 1, wc = w & 1;
    int lr = lane & 15, lkg = lane >> 4;

    auto stage = [&](int bsel, int k0) {
        #pragma unroll
        for (int q = 0; q < 2; ++q) {
            int idx = q*256 + tid;           // 0..511; dest = idx*16B, kg wave-uniform
            int kg = idx >> 7, row = idx & 127;
            gload16(Ab + (long)(i0+row)*K + k0 + kg*8, As[bsel] + (size_t)idx*8);
            gload16(Bb + (long)(j0+row)*K + k0 + kg*8, Bs[bsel] + (size_t)idx*8);
        }
    };

    v4f acc[4][4];
    #pragma unroll
    for (int i = 0; i < 4; ++i)
        #pragma unroll
        for (int j = 0; j < 4; ++j) { v4f z = {0.f,0.f,0.f,0.f}; acc[i][j] = z; }

    stage(0, 0);
    __syncthreads();
    int cur = 0;
    for (int k0 = 0; k0 < K; k0 += 32) {
        if (k0 + 32 < K) stage(cur ^ 1, k0 + 32);
        v8h af[4], bfr[4];
        #pragma unroll
        for (int mf = 0; mf < 4; ++mf)
            af[mf] = *(const v8h*)(As[cur] + lkg*1024 + (wr*64 + mf*16 + lr)*8);
        #pragma unroll
        for (int nf = 0; nf < 4; ++nf)
            bfr[nf] = *(const v8h*)(Bs[cur] + lkg*1024 + (wc*64 + nf*16 + lr)*8);
        __builtin_amdgcn_s_setprio(1);
        #pragma unroll
        for (int mf = 0; mf < 4; ++mf)
            #pragma unroll
            for (int nf = 0; nf < 4; ++nf)
                acc[mf][nf] = __builtin_amdgcn_mfma_f32_16x16x32_f16(af[mf], bfr[nf], acc[mf][nf], 0, 0, 0);
        __builtin_amdgcn_s_setprio(0);
        __syncthreads();
        cur ^= 1;
    }

    int rbase = (lane >> 4) * 4;
    #pragma unroll
    for (int mf = 0; mf < 4; ++mf) {
        #pragma unroll
        for (int nf = 0; nf < 4; ++nf) {
            #pragma unroll
            for (int r = 0; r < 4; ++r) {
                int row = i0 + wr*64 + mf*16 + rbase + r;
                int col = j0 + wc*64 + nf*16 + lr;
                float v = acc[mf][nf][r];
                if (EPI == 0) {
                    v += bias[row];
                    ((HF*)Cv + (long)b*sC)[(long)row*N + col] = (HF)v;
                } else if (EPI == 3) {
                    v += bias[col];
                    ((HF*)Cv + (long)b*sC)[(long)row*N + col] = (HF)v;
                } else {
                    float* Cf = (float*)Cv + (long)b*sC;
                    const float* Xb = Xres + (long)b*sX;
                    long o = (long)row*N + col;
                    Cf[o] = v * rowScale[row] + rowShift[row] + Xb[o];
                }
            }
        }
    }
}

// ---------------- fused flash attention v6 ----------------
// 512 blocks x 128 thr (2 waves x 32 rows). batch = bid&7 (XCD-pinned), 2 blocks/CU.
// P AND G double-buffered in LDS via gload_lds, k-group-major (conflict-free, 0 swizzle).
// R=32 rows/wave halves per-row B-fragment LDS traffic vs R=16.
__global__ __launch_bounds__(128) void fused_attn_kernel(
    const HF* __restrict__ TP,   // [B][4096][512], theta = cols 0..255
    const HF* __restrict__ Pt,   // [B][1024][256]
    const HF* __restrict__ G,    // [B][256][1024]
    HF* __restrict__ Yt)         // [B][4096][256]
{
    __shared__ alignas(16) HF P_lds[2][8192];   // [32 kg][32 row][8]
    __shared__ alignas(16) HF G_lds[2][8192];   // [4 kg][256 row][8]
    __shared__ alignas(16) HF P_buf[2][32][36]; // padded stride 72B (0-conflict measured)

    int bid = blockIdx.x;
    int b = bid & 7;
    int ntile = bid >> 3;          // 0..63
    int tid = threadIdx.x;
    int lane = tid & 63, w = tid >> 6;   // w in {0,1}
    int lr = lane & 15, lkg = lane >> 4;
    int nbase = ntile * 64 + w * 32;

    const HF* Tq = TP + ((long)b*HW + nbase) * 512;
    const HF* Pb = Pt + (long)b*Mp*CI;
    const HF* Gb = G  + (long)b*CI*Mp;

    auto stage = [&](int bsel, int m0) {
        #pragma unroll
        for (int q = 0; q < 8; ++q) {
            int seg = w*8 + q;                      // 0..15 (16B-seg group of 64 lanes)
            int idx = seg*64 + lane;                // 0..1023
            // P: [32 kg][32 row][8]  (per-lane global src; linear LDS dest)
            int pkg = idx >> 5, prow = idx & 31;
            gload16(Pb + (long)(m0 + prow)*CI + pkg*8, P_lds[bsel] + (size_t)idx*8);
            // G: [4 kg][256 row][8]
            int gkg = seg >> 2, grow = (seg & 3)*64 + lane;
            gload16(Gb + (long)grow*Mp + m0 + gkg*8, G_lds[bsel] + (size_t)idx*8);
        }
    };

    // Q fragments: 2 row-tiles x 8 k-frags, registers for whole kernel
    v8h af[2][8];
    #pragma unroll
    for (int rt = 0; rt < 2; ++rt)
        #pragma unroll
        for (int kf = 0; kf < 8; ++kf)
            af[rt][kf] = *(const v8h*)(Tq + (long)(rt*16 + lr)*512 + kf*32 + lkg*8);

    v4f acc_y[2][16];
    #pragma unroll
    for (int rt = 0; rt < 2; ++rt)
        #pragma unroll
        for (int i = 0; i < 16; ++i) { v4f z = {0.f,0.f,0.f,0.f}; acc_y[rt][i] = z; }
    float mrun[2][4] = {{-1e30f,-1e30f,-1e30f,-1e30f},{-1e30f,-1e30f,-1e30f,-1e30f}};
    float lsum[2][4] = {{0.f,0.f,0.f,0.f},{0.f,0.f,0.f,0.f}};

    stage(0, 0);
    __syncthreads();

    int cur = 0;
    for (int t = 0; t < 32; ++t) {
        if (t < 31) stage(cur ^ 1, (t+1)*32);

        // QK^T: S[32 n][32 m]
        v4f acc[2][2];
        #pragma unroll
        for (int rt = 0; rt < 2; ++rt)
            #pragma unroll
            for (int nf = 0; nf < 2; ++nf) { v4f z = {0.f,0.f,0.f,0.f}; acc[rt][nf] = z; }
        __builtin_amdgcn_s_setprio(1);
        #pragma unroll
        for (int kf = 0; kf < 8; ++kf) {
            #pragma unroll
            for (int nf = 0; nf < 2; ++nf) {
                v8h bfr = *(const v8h*)(P_lds[cur] + (kf*4 + lkg)*256 + (nf*16 + lr)*8);
                acc[0][nf] = __builtin_amdgcn_mfma_f32_16x16x32_f16(af[0][kf], bfr, acc[0][nf], 0, 0, 0);
                acc[1][nf] = __builtin_amdgcn_mfma_f32_16x16x32_f16(af[1][kf], bfr, acc[1][nf], 0, 0, 0);
            }
        }
        __builtin_amdgcn_s_setprio(0);

        // online softmax per row-tile
        #pragma unroll
        for (int rt = 0; rt < 2; ++rt) {
            #pragma unroll
            for (int r = 0; r < 4; ++r) {
                float cm = fmaxf(acc[rt][0][r], acc[rt][1][r]);
                #pragma unroll
                for (int d = 1; d < 16; d <<= 1) cm = fmaxf(cm, __shfl_xor(cm, d));
                if (cm > mrun[rt][r]) {
                    float alpha = __expf(mrun[rt][r] - cm);
                    mrun[rt][r] = cm;
                    lsum[rt][r] *= alpha;
                    #pragma unroll
                    for (int cf = 0; cf < 16; ++cf) acc_y[rt][cf][r] *= alpha;
                }
                int row = rt*16 + lkg*4 + r;
                #pragma unroll
                for (int nf = 0; nf < 2; ++nf) {
                    float p = __expf(acc[rt][nf][r] - mrun[rt][r]);   // <= 1
                    lsum[rt][r] += p;
                    P_buf[w][row][nf*16 + lr] = (HF)p;
                }
            }
        }

        // PV: Y[32 n][256 c] += P(32x32) @ G_chunk^T, G from LDS
        v8h ap0, ap1;
        {
            v4h a0 = *(const v4h*)(&P_buf[w][lr][lkg*8]);
            v4h a1 = *(const v4h*)(&P_buf[w][lr][lkg*8 + 4]);
            ap0 = __builtin_shufflevector(a0, a1, 0,1,2,3,4,5,6,7);
            v4h b0 = *(const v4h*)(&P_buf[w][16 + lr][lkg*8]);
            v4h b1 = *(const v4h*)(&P_buf[w][16 + lr][lkg*8 + 4]);
            ap1 = __builtin_shufflevector(b0, b1, 0,1,2,3,4,5,6,7);
        }
        __builtin_amdgcn_s_setprio(1);
        #pragma unroll
        for (int cf = 0; cf < 16; ++cf) {
            v8h bg = *(const v8h*)(G_lds[cur] + lkg*2048 + (cf*16 + lr)*8);
            acc_y[0][cf] = __builtin_amdgcn_mfma_f32_16x16x32_f16(ap0, bg, acc_y[0][cf], 0, 0, 0);
            acc_y[1][cf] = __builtin_amdgcn_mfma_f32_16x16x32_f16(ap1, bg, acc_y[1][cf], 0, 0, 0);
        }
        __builtin_amdgcn_s_setprio(0);

        __syncthreads();   // drains gload_lds for cur^1; all waves done reading cur
        cur ^= 1;
    }

    // epilogue: cross-lane sum reduce, Y /= l, write f16
    HF* Yb = Yt + ((long)b*HW + nbase) * CI;
    #pragma unroll
    for (int rt = 0; rt < 2; ++rt) {
        #pragma unroll
        for (int r = 0; r < 4; ++r) {
            float s = lsum[rt][r];
            #pragma unroll
            for (int d = 1; d < 16; d <<= 1) s += __shfl_xor(s, d);
            float inv = 1.f / s;
            #pragma unroll
            for (int cf = 0; cf < 16; ++cf)
                Yb[(long)(rt*16 + lkg*4 + r)*CI + cf*16 + lr] = (HF)(acc_y[rt][cf][r] * inv);
        }
    }
}

extern "C" void kernel_launch(void* const* d_in, const int* in_sizes, int n_in,
                              void* d_out, int out_size, void* d_ws, size_t ws_size,
                              hipStream_t stream)
{
    const float* x     = (const float*)d_in[0];
    const float* w_g   = (const float*)d_in[1];
    const float* b_g   = (const float*)d_in[2];
    const float* w_th  = (const float*)d_in[3];
    const float* b_th  = (const float*)d_in[4];
    const float* w_ph  = (const float*)d_in[5];
    const float* b_ph  = (const float*)d_in[6];
    const float* w_out = (const float*)d_in[7];
    const float* b_out = (const float*)d_in[8];
    const float* gamma = (const float*)d_in[9];
    const float* beta  = (const float*)d_in[10];
    const float* mean  = (const float*)d_in[11];
    const float* var   = (const float*)d_in[12];
    float* out = (float*)d_out;

    char* ws = (char*)d_ws;
    size_t off = 0;
    auto alloc = [&](size_t bytes) { void* p = ws + off; off += (bytes + 255) & ~(size_t)255; return p; };
    HF*    wall  = (HF*)alloc((size_t)768*512*2);   // rows: theta 0-255, phi 256-511, g 512-767
    float* ball  = (float*)alloc(768*4);
    HF*    wo    = (HF*)alloc((size_t)512*256*2);
    float* scale = (float*)alloc(512*4);
    float* shift = (float*)alloc(512*4);
    HF*    xT    = (HF*)alloc((size_t)Bn*HW*Cc*2);
    HF*    TP    = (HF*)alloc((size_t)Bn*HW*512*2);  // [s][theta|phi]
    HF*    Gg    = (HF*)alloc((size_t)Bn*CI*HW*2);   // g conv, c-major
    HF*    Pt    = (HF*)alloc((size_t)Bn*Mp*CI*2);
    HF*    G     = (HF*)alloc((size_t)Bn*CI*Mp*2);
    HF*    Yt    = (HF*)alloc((size_t)Bn*HW*CI*2);

    prep_kernel<<<1536, 256, 0, stream>>>(w_g,b_g,w_th,b_th,w_ph,b_ph,w_out,b_out,gamma,beta,mean,var,
                                          wall, ball, wo, scale, shift);
    transpose_x_kernel<<<dim3(64,8,Bn), 256, 0, stream>>>(x, xT);
    // TP[b, s, o] = xT @ {w_th|w_ph}^T + colBias  (theta+phi, s-major: no transpose needed)
    gemm_bt_kernel<3><<<dim3(4,32,Bn), 256, 0, stream>>>(xT, (long)HW*Cc, wall, 0, TP, (long)HW*512,
                                                         HW, 512, Cc, ball, nullptr, nullptr, nullptr, 0);
    // Gg[b, c, s] = w_g @ xT^T + rowBias  (c-major for PV's G[c][m] layout)
    gemm_bt_kernel<0><<<dim3(32,2,Bn), 256, 0, stream>>>(wall + (size_t)512*512, 0, xT, (long)HW*Cc,
                                                         Gg, (long)CI*HW, CI, HW, Cc, ball + 512,
                                                         nullptr, nullptr, nullptr, 0);
    // phi -> pooled Pt[b, m, c] straight from TP
    pool_sm_kernel<<<1024, 256, 0, stream>>>(TP, Pt);
    // g -> pooled G[b, c, m]
    pool_kernel<<<8192, 256, 0, stream>>>(Gg, (long)CI*HW, G, (long)CI*Mp);
    // fused scores+softmax+PV -> Yt[b, n, c]
    fused_attn_kernel<<<512, 128, 0, stream>>>(TP, Pt, G, Yt);
    // out[b, co, n] = wo @ Yt^T * scale + shift + x
    gemm_bt_kernel<2><<<dim3(32,4,Bn), 256, 0, stream>>>(wo, 0, Yt, (long)HW*CI, out, (long)Cc*HW,
                                                         Cc, HW, CI, nullptr, scale, shift, x, (long)Cc*HW);
}

// Round 8
// 218.155 us; speedup vs baseline: 1.4836x; 1.3871x over previous
//
#include <hip/hip_runtime.h>

typedef _Float16 v8h __attribute__((ext_vector_type(8)));
typedef _Float16 v4h __attribute__((ext_vector_type(4)));
typedef float v4f __attribute__((ext_vector_type(4)));
#define HF _Float16

// dims
#define Bn 8
#define Cc 512
#define CI 256
#define HW 4096   // 64*64
#define Mp 1024   // 32*32 pooled

__device__ __forceinline__ void gload16(const void* g, void* l) {
    __builtin_amdgcn_global_load_lds((const __attribute__((address_space(1))) void*)g,
                                     (__attribute__((address_space(3))) void*)l, 16, 0, 0);
}

// ---------------- prep: weights fp32->f16, BN fold ----------------
__global__ __launch_bounds__(256) void prep_kernel(
    const float* __restrict__ w_g, const float* __restrict__ b_g,
    const float* __restrict__ w_th, const float* __restrict__ b_th,
    const float* __restrict__ w_ph, const float* __restrict__ b_ph,
    const float* __restrict__ w_out, const float* __restrict__ b_out,
    const float* __restrict__ gamma, const float* __restrict__ beta,
    const float* __restrict__ mean, const float* __restrict__ var,
    HF* __restrict__ wall, float* __restrict__ ball,
    HF* __restrict__ wo, float* __restrict__ scale, float* __restrict__ shift)
{
    int idx = blockIdx.x * 256 + threadIdx.x;
    if (idx < 768*512) {
        int o = idx >> 9;
        float v = (o < 256) ? w_th[idx] : (o < 512) ? w_ph[idx - 256*512] : w_g[idx - 512*512];
        wall[idx] = (HF)v;
    }
    if (idx < 512*256) wo[idx] = (HF)w_out[idx];
    if (idx < 768) ball[idx] = (idx < 256) ? b_th[idx] : (idx < 512) ? b_ph[idx-256] : b_g[idx-512];
    if (idx < 512) {
        float inv = gamma[idx] * rsqrtf(var[idx] + 1e-5f);
        scale[idx] = inv;
        shift[idx] = (b_out[idx] - mean[idx]) * inv + beta[idx];
    }
}

// ---------------- transpose x: (b,c,s) fp32 -> xT (b,s,c) f16 ----------------
__global__ __launch_bounds__(256) void transpose_x_kernel(const float* __restrict__ x, HF* __restrict__ xT)
{
    __shared__ float tile[64][65];
    int b = blockIdx.z;
    int c0 = blockIdx.y * 64, s0 = blockIdx.x * 64;
    int tr = threadIdx.x >> 6, ts = threadIdx.x & 63;
    #pragma unroll
    for (int i = 0; i < 16; ++i) {
        int r = tr + i*4;
        tile[r][ts] = x[((long)(b*Cc) + c0 + r)*HW + s0 + ts];
    }
    __syncthreads();
    #pragma unroll
    for (int i = 0; i < 16; ++i) {
        int r = tr + i*4;
        xT[((long)b*HW + s0 + r)*Cc + c0 + ts] = (HF)tile[ts][r];
    }
}

// ---------------- 2x2 maxpool from s-major phi: Ph[s, c] -> Pt[m, c] ----------------
__global__ __launch_bounds__(256) void pool_sm_kernel(const HF* __restrict__ TP, HF* __restrict__ Pt)
{
    int idx = blockIdx.x * 256 + threadIdx.x;   // Bn*1024*32
    int c8 = idx & 31;
    int m  = (idx >> 5) & 1023;
    int b  = idx >> 15;
    int h2 = m >> 5, w2 = m & 31;
    int s00 = h2*128 + w2*2;
    const HF* base = TP + ((long)b*HW + s00)*512 + 256 + c8*8;
    v8h a0 = *(const v8h*)(base);
    v8h a1 = *(const v8h*)(base + 512);
    v8h a2 = *(const v8h*)(base + 64*512);
    v8h a3 = *(const v8h*)(base + 65*512);
    v8h o;
    #pragma unroll
    for (int j = 0; j < 8; ++j) {
        float v = fmaxf(fmaxf((float)a0[j], (float)a1[j]), fmaxf((float)a2[j], (float)a3[j]));
        o[j] = (HF)v;
    }
    *(v8h*)(Pt + ((long)b*Mp + m)*CI + c8*8) = o;
}

// ---------------- 2x2 maxpool c-major: Gg (b,c,64,64) -> G (b,c,32,32) ----------------
__global__ __launch_bounds__(256) void pool_kernel(const HF* __restrict__ src, long sSrc,
                                                   HF* __restrict__ dst, long sDst)
{
    long idx = (long)blockIdx.x * 256 + threadIdx.x;   // Bn*256*1024
    int m = idx & 1023;
    long bc = idx >> 10;
    int c = (int)(bc & 255);
    int b = (int)(bc >> 8);
    int h2 = m >> 5, w2 = m & 31;
    const HF* p = src + (long)b*sSrc + (long)c*HW + h2*128 + w2*2;
    float v = fmaxf(fmaxf((float)p[0], (float)p[1]), fmaxf((float)p[64], (float)p[65]));
    dst[(long)b*sDst + (long)c*Mp + m] = (HF)v;
}

// ---------------- generic tiled gemm_bt: C[i,j] = sum_k A[i,k]*B[j,k] ----------------
// round-3 internals (measured fastest here): reg-staged, [128][40] padded LDS, 2 barriers/step.
// EPI 0: f16 = acc + rowBias[i];  EPI 2: f32 = acc*scale[i]+shift[i]+X;  EPI 3: f16 = acc + colBias[j]
template<int EPI>
__global__ __launch_bounds__(256) void gemm_bt_kernel(
    const HF* __restrict__ A, long sA, const HF* __restrict__ B, long sB,
    void* __restrict__ Cv, long sC, int M, int N, int K,
    const float* __restrict__ bias,
    const float* __restrict__ rowScale, const float* __restrict__ rowShift,
    const float* __restrict__ Xres, long sX)
{
    __shared__ HF As[128][40];
    __shared__ HF Bs[128][40];
    int b = blockIdx.z;
    int i0 = blockIdx.y * 128;
    int j0 = blockIdx.x * 128;
    const HF* Ab = A + (long)b * sA;
    const HF* Bb = B + (long)b * sB;
    int tid = threadIdx.x;
    int lane = tid & 63, w = tid >> 6;
    int wr = w >> 1, wc = w & 1;
    int lr = lane & 15, lk = (lane >> 4) * 8;

    v4f acc[4][4];
    #pragma unroll
    for (int i = 0; i < 4; ++i)
        #pragma unroll
        for (int j = 0; j < 4; ++j) { v4f z = {0.f,0.f,0.f,0.f}; acc[i][j] = z; }

    for (int k0 = 0; k0 < K; k0 += 32) {
        #pragma unroll
        for (int q = 0; q < 2; ++q) {
            int ch = tid*2 + q;          // 0..511
            int row = ch >> 2;
            int c8 = (ch & 3) * 8;
            const uint4* ga = (const uint4*)(Ab + (long)(i0+row)*K + k0 + c8);
            *(uint4*)(&As[row][c8]) = *ga;
            const uint4* gb = (const uint4*)(Bb + (long)(j0+row)*K + k0 + c8);
            *(uint4*)(&Bs[row][c8]) = *gb;
        }
        __syncthreads();
        v8h af[4], bfr[4];
        #pragma unroll
        for (int mf = 0; mf < 4; ++mf)
            af[mf] = *(const v8h*)(&As[wr*64 + mf*16 + lr][lk]);
        #pragma unroll
        for (int nf = 0; nf < 4; ++nf)
            bfr[nf] = *(const v8h*)(&Bs[wc*64 + nf*16 + lr][lk]);
        #pragma unroll
        for (int mf = 0; mf < 4; ++mf)
            #pragma unroll
            for (int nf = 0; nf < 4; ++nf)
                acc[mf][nf] = __builtin_amdgcn_mfma_f32_16x16x32_f16(af[mf], bfr[nf], acc[mf][nf], 0, 0, 0);
        __syncthreads();
    }

    int rbase = (lane >> 4) * 4;
    #pragma unroll
    for (int mf = 0; mf < 4; ++mf) {
        #pragma unroll
        for (int nf = 0; nf < 4; ++nf) {
            #pragma unroll
            for (int r = 0; r < 4; ++r) {
                int row = i0 + wr*64 + mf*16 + rbase + r;
                int col = j0 + wc*64 + nf*16 + lr;
                float v = acc[mf][nf][r];
                if (EPI == 0) {
                    v += bias[row];
                    ((HF*)Cv + (long)b*sC)[(long)row*N + col] = (HF)v;
                } else if (EPI == 3) {
                    v += bias[col];
                    ((HF*)Cv + (long)b*sC)[(long)row*N + col] = (HF)v;
                } else {
                    float* Cf = (float*)Cv + (long)b*sC;
                    const float* Xb = Xres + (long)b*sX;
                    long o = (long)row*N + col;
                    Cf[o] = v * rowScale[row] + rowShift[row] + Xb[o];
                }
            }
        }
    }
}

// ---------------- fused flash attention v7 ----------------
// round-5 structure (measured 99us): 512 blocks x 256 thr (4 waves x 16 rows),
// 2 blocks/CU = 2 waves/SIMD. P+G double-buffered in LDS via gload_lds,
// k-group-major (0 conflicts measured). batch = bid&7 (XCD-pinned, FETCH -3x).
// NEW: T13 defer-rescale THR=7 (p <= e^7 = 1096, f16-safe; skips most rescales).
__global__ __launch_bounds__(256, 2) void fused_attn_kernel(
    const HF* __restrict__ TP,   // [B][4096][512], theta = cols 0..255
    const HF* __restrict__ Pt,   // [B][1024][256]
    const HF* __restrict__ G,    // [B][256][1024]
    HF* __restrict__ Yt)         // [B][4096][256]
{
    __shared__ alignas(16) HF P_lds[2][8192];   // [32 kg][32 row][8]
    __shared__ alignas(16) HF G_lds[2][8192];   // [4 kg][256 row][8]
    __shared__ alignas(16) HF P_buf[4][16][36]; // padded stride 72B (0-conflict measured)

    int bid = blockIdx.x;
    int b = bid & 7;
    int ntile = bid >> 3;          // 0..63
    int tid = threadIdx.x;
    int lane = tid & 63, w = tid >> 6;
    int lr = lane & 15, lkg = lane >> 4;
    int nbase = ntile * 64 + w * 16;

    const HF* Tq = TP + ((long)b*HW + nbase) * 512;
    const HF* Pb = Pt + (long)b*Mp*CI;
    const HF* Gb = G  + (long)b*CI*Mp;

    auto stage = [&](int bsel, int m0) {
        #pragma unroll
        for (int q = 0; q < 4; ++q) {
            int idxp = (w*4 + q)*64 + lane;         // 0..1023; dest = idxp*16B
            int pkg = idxp >> 5, prow = idxp & 31;  // [32 kg][32 row][8]
            gload16(Pb + (long)(m0 + prow)*CI + pkg*8, P_lds[bsel] + (size_t)idxp*8);
            int grow = q*64 + lane;                 // kg = w (wave-uniform)
            gload16(Gb + (long)grow*Mp + m0 + w*8, G_lds[bsel] + ((size_t)w*256 + grow)*8);
        }
    };

    // Q fragments in registers for whole kernel (theta cols of TP)
    v8h af[8];
    #pragma unroll
    for (int kf = 0; kf < 8; ++kf)
        af[kf] = *(const v8h*)(Tq + (long)lr*512 + kf*32 + lkg*8);

    v4f acc_y[16];
    #pragma unroll
    for (int i = 0; i < 16; ++i) { v4f z = {0.f,0.f,0.f,0.f}; acc_y[i] = z; }
    float mrun[4] = {-1e30f,-1e30f,-1e30f,-1e30f};
    float lsum[4] = {0.f,0.f,0.f,0.f};

    stage(0, 0);
    __syncthreads();

    int cur = 0;
    for (int t = 0; t < 32; ++t) {
        if (t < 31) stage(cur ^ 1, (t+1)*32);

        // QK^T: S[16 n][32 m]
        v4f acc[2];
        #pragma unroll
        for (int nf = 0; nf < 2; ++nf) { v4f z = {0.f,0.f,0.f,0.f}; acc[nf] = z; }
        __builtin_amdgcn_s_setprio(1);
        #pragma unroll
        for (int kf = 0; kf < 8; ++kf) {
            #pragma unroll
            for (int nf = 0; nf < 2; ++nf) {
                v8h bfr = *(const v8h*)(P_lds[cur] + (kf*4 + lkg)*256 + (nf*16 + lr)*8);
                acc[nf] = __builtin_amdgcn_mfma_f32_16x16x32_f16(af[kf], bfr, acc[nf], 0, 0, 0);
            }
        }
        __builtin_amdgcn_s_setprio(0);

        // online softmax with defer-rescale (THR=7: p <= e^7 fits f16)
        #pragma unroll
        for (int r = 0; r < 4; ++r) {
            float cm = fmaxf(acc[0][r], acc[1][r]);
            #pragma unroll
            for (int d = 1; d < 16; d <<= 1) cm = fmaxf(cm, __shfl_xor(cm, d));
            if (cm > mrun[r] + 7.f) {                 // uniform across the row's 16 lanes
                float alpha = __expf(mrun[r] - cm);   // first time: exp(-inf)=0, zeroes nothing
                mrun[r] = cm;
                lsum[r] *= alpha;
                #pragma unroll
                for (int cf = 0; cf < 16; ++cf) acc_y[cf][r] *= alpha;
            }
            int row = lkg*4 + r;
            #pragma unroll
            for (int nf = 0; nf < 2; ++nf) {
                float p = __expf(acc[nf][r] - mrun[r]);   // <= e^7 = 1096
                lsum[r] += p;
                P_buf[w][row][nf*16 + lr] = (HF)p;
            }
        }

        // PV: Y[16 n][256 c] += P(16x32) @ G_chunk^T, G from LDS
        v8h ap;
        {
            v4h a0 = *(const v4h*)(&P_buf[w][lr][lkg*8]);
            v4h a1 = *(const v4h*)(&P_buf[w][lr][lkg*8 + 4]);
            ap = __builtin_shufflevector(a0, a1, 0,1,2,3,4,5,6,7);
        }
        __builtin_amdgcn_s_setprio(1);
        #pragma unroll
        for (int cf = 0; cf < 16; ++cf) {
            v8h bg = *(const v8h*)(G_lds[cur] + lkg*2048 + (cf*16 + lr)*8);
            acc_y[cf] = __builtin_amdgcn_mfma_f32_16x16x32_f16(ap, bg, acc_y[cf], 0, 0, 0);
        }
        __builtin_amdgcn_s_setprio(0);

        __syncthreads();   // drains gload_lds for cur^1; all waves done reading cur
        cur ^= 1;
    }

    // epilogue: cross-lane sum reduce, Y /= l, write f16
    HF* Yb = Yt + ((long)b*HW + nbase) * CI;
    #pragma unroll
    for (int r = 0; r < 4; ++r) {
        float s = lsum[r];
        #pragma unroll
        for (int d = 1; d < 16; d <<= 1) s += __shfl_xor(s, d);
        float inv = 1.f / s;
        #pragma unroll
        for (int cf = 0; cf < 16; ++cf)
            Yb[(long)(lkg*4 + r)*CI + cf*16 + lr] = (HF)(acc_y[cf][r] * inv);
    }
}

extern "C" void kernel_launch(void* const* d_in, const int* in_sizes, int n_in,
                              void* d_out, int out_size, void* d_ws, size_t ws_size,
                              hipStream_t stream)
{
    const float* x     = (const float*)d_in[0];
    const float* w_g   = (const float*)d_in[1];
    const float* b_g   = (const float*)d_in[2];
    const float* w_th  = (const float*)d_in[3];
    const float* b_th  = (const float*)d_in[4];
    const float* w_ph  = (const float*)d_in[5];
    const float* b_ph  = (const float*)d_in[6];
    const float* w_out = (const float*)d_in[7];
    const float* b_out = (const float*)d_in[8];
    const float* gamma = (const float*)d_in[9];
    const float* beta  = (const float*)d_in[10];
    const float* mean  = (const float*)d_in[11];
    const float* var   = (const float*)d_in[12];
    float* out = (float*)d_out;

    char* ws = (char*)d_ws;
    size_t off = 0;
    auto alloc = [&](size_t bytes) { void* p = ws + off; off += (bytes + 255) & ~(size_t)255; return p; };
    HF*    wall  = (HF*)alloc((size_t)768*512*2);   // rows: theta 0-255, phi 256-511, g 512-767
    float* ball  = (float*)alloc(768*4);
    HF*    wo    = (HF*)alloc((size_t)512*256*2);
    float* scale = (float*)alloc(512*4);
    float* shift = (float*)alloc(512*4);
    HF*    xT    = (HF*)alloc((size_t)Bn*HW*Cc*2);
    HF*    TP    = (HF*)alloc((size_t)Bn*HW*512*2);  // [s][theta|phi]
    HF*    Gg    = (HF*)alloc((size_t)Bn*CI*HW*2);   // g conv, c-major
    HF*    Pt    = (HF*)alloc((size_t)Bn*Mp*CI*2);
    HF*    G     = (HF*)alloc((size_t)Bn*CI*Mp*2);
    HF*    Yt    = (HF*)alloc((size_t)Bn*HW*CI*2);

    prep_kernel<<<1536, 256, 0, stream>>>(w_g,b_g,w_th,b_th,w_ph,b_ph,w_out,b_out,gamma,beta,mean,var,
                                          wall, ball, wo, scale, shift);
    transpose_x_kernel<<<dim3(64,8,Bn), 256, 0, stream>>>(x, xT);
    // TP[b, s, o] = xT @ {w_th|w_ph}^T + colBias  (theta+phi, s-major: no transpose needed)
    gemm_bt_kernel<3><<<dim3(4,32,Bn), 256, 0, stream>>>(xT, (long)HW*Cc, wall, 0, TP, (long)HW*512,
                                                         HW, 512, Cc, ball, nullptr, nullptr, nullptr, 0);
    // Gg[b, c, s] = w_g @ xT^T + rowBias  (c-major for PV's G[c][m] layout)
    gemm_bt_kernel<0><<<dim3(32,2,Bn), 256, 0, stream>>>(wall + (size_t)512*512, 0, xT, (long)HW*Cc,
                                                         Gg, (long)CI*HW, CI, HW, Cc, ball + 512,
                                                         nullptr, nullptr, nullptr, 0);
    // phi -> pooled Pt[b, m, c] straight from TP
    pool_sm_kernel<<<1024, 256, 0, stream>>>(TP, Pt);
    // g -> pooled G[b, c, m]
    pool_kernel<<<8192, 256, 0, stream>>>(Gg, (long)CI*HW, G, (long)CI*Mp);
    // fused scores+softmax+PV -> Yt[b, n, c]
    fused_attn_kernel<<<512, 256, 0, stream>>>(TP, Pt, G, Yt);
    // out[b, co, n] = wo @ Yt^T * scale + shift + x
    gemm_bt_kernel<2><<<dim3(32,4,Bn), 256, 0, stream>>>(wo, 0, Yt, (long)HW*CI, out, (long)Cc*HW,
                                                         Cc, HW, CI, nullptr, scale, shift, x, (long)Cc*HW);
}

// Round 11
// 206.032 us; speedup vs baseline: 1.5709x; 1.0588x over previous
//
#include <hip/hip_runtime.h>

typedef _Float16 v8h __attribute__((ext_vector_type(8)));
typedef _Float16 v4h __attribute__((ext_vector_type(4)));
typedef float v4f __attribute__((ext_vector_type(4)));
#define HF _Float16

// dims
#define Bn 8
#define Cc 512
#define CI 256
#define HW 4096   // 64*64
#define Mp 1024   // 32*32 pooled

__device__ __forceinline__ void gload16(const void* g, void* l) {
    __builtin_amdgcn_global_load_lds((const __attribute__((address_space(1))) void*)g,
                                     (__attribute__((address_space(3))) void*)l, 16, 0, 0);
}

// ---------------- prep: weights fp32->f16, BN fold ----------------
__global__ __launch_bounds__(256) void prep_kernel(
    const float* __restrict__ w_g, const float* __restrict__ b_g,
    const float* __restrict__ w_th, const float* __restrict__ b_th,
    const float* __restrict__ w_ph, const float* __restrict__ b_ph,
    const float* __restrict__ w_out, const float* __restrict__ b_out,
    const float* __restrict__ gamma, const float* __restrict__ beta,
    const float* __restrict__ mean, const float* __restrict__ var,
    HF* __restrict__ wall, float* __restrict__ ball,
    HF* __restrict__ wo, float* __restrict__ scale, float* __restrict__ shift)
{
    int idx = blockIdx.x * 256 + threadIdx.x;
    if (idx < 768*512) {
        int o = idx >> 9;
        float v = (o < 256) ? w_th[idx] : (o < 512) ? w_ph[idx - 256*512] : w_g[idx - 512*512];
        wall[idx] = (HF)v;
    }
    if (idx < 512*256) wo[idx] = (HF)w_out[idx];
    if (idx < 768) ball[idx] = (idx < 256) ? b_th[idx] : (idx < 512) ? b_ph[idx-256] : b_g[idx-512];
    if (idx < 512) {
        float inv = gamma[idx] * rsqrtf(var[idx] + 1e-5f);
        scale[idx] = inv;
        shift[idx] = (b_out[idx] - mean[idx]) * inv + beta[idx];
    }
}

// ---------------- transpose x: (b,c,s) fp32 -> xT (b,s,c) f16 ----------------
__global__ __launch_bounds__(256) void transpose_x_kernel(const float* __restrict__ x, HF* __restrict__ xT)
{
    __shared__ float tile[64][65];
    int b = blockIdx.z;
    int c0 = blockIdx.y * 64, s0 = blockIdx.x * 64;
    int tr = threadIdx.x >> 6, ts = threadIdx.x & 63;
    #pragma unroll
    for (int i = 0; i < 16; ++i) {
        int r = tr + i*4;
        tile[r][ts] = x[((long)(b*Cc) + c0 + r)*HW + s0 + ts];
    }
    __syncthreads();
    #pragma unroll
    for (int i = 0; i < 16; ++i) {
        int r = tr + i*4;
        xT[((long)b*HW + s0 + r)*Cc + c0 + ts] = (HF)tile[ts][r];
    }
}

// ---------------- 2x2 maxpool from s-major phi: Ph[s, c] -> Pt[m, c] ----------------
__global__ __launch_bounds__(256) void pool_sm_kernel(const HF* __restrict__ TP, HF* __restrict__ Pt)
{
    int idx = blockIdx.x * 256 + threadIdx.x;   // Bn*1024*32
    int c8 = idx & 31;
    int m  = (idx >> 5) & 1023;
    int b  = idx >> 15;
    int h2 = m >> 5, w2 = m & 31;
    int s00 = h2*128 + w2*2;
    const HF* base = TP + ((long)b*HW + s00)*512 + 256 + c8*8;
    v8h a0 = *(const v8h*)(base);
    v8h a1 = *(const v8h*)(base + 512);
    v8h a2 = *(const v8h*)(base + 64*512);
    v8h a3 = *(const v8h*)(base + 65*512);
    v8h o;
    #pragma unroll
    for (int j = 0; j < 8; ++j) {
        float v = fmaxf(fmaxf((float)a0[j], (float)a1[j]), fmaxf((float)a2[j], (float)a3[j]));
        o[j] = (HF)v;
    }
    *(v8h*)(Pt + ((long)b*Mp + m)*CI + c8*8) = o;
}

// ---------------- 2x2 maxpool c-major: Gg (b,c,64,64) -> G (b,c,32,32) ----------------
__global__ __launch_bounds__(256) void pool_kernel(const HF* __restrict__ src, long sSrc,
                                                   HF* __restrict__ dst, long sDst)
{
    long idx = (long)blockIdx.x * 256 + threadIdx.x;   // Bn*256*1024
    int m = idx & 1023;
    long bc = idx >> 10;
    int c = (int)(bc & 255);
    int b = (int)(bc >> 8);
    int h2 = m >> 5, w2 = m & 31;
    const HF* p = src + (long)b*sSrc + (long)c*HW + h2*128 + w2*2;
    float v = fmaxf(fmaxf((float)p[0], (float)p[1]), fmaxf((float)p[64], (float)p[65]));
    dst[(long)b*sDst + (long)c*Mp + m] = (HF)v;
}

// ---------------- generic tiled gemm_bt: C[i,j] = sum_k A[i,k]*B[j,k] ----------------
// reg-staged, [128][40] padded LDS, 2 barriers/step (measured fastest here).
template<int EPI>
__global__ __launch_bounds__(256) void gemm_bt_kernel(
    const HF* __restrict__ A, long sA, const HF* __restrict__ B, long sB,
    void* __restrict__ Cv, long sC, int M, int N, int K,
    const float* __restrict__ bias,
    const float* __restrict__ rowScale, const float* __restrict__ rowShift,
    const float* __restrict__ Xres, long sX)
{
    __shared__ HF As[128][40];
    __shared__ HF Bs[128][40];
    int b = blockIdx.z;
    int i0 = blockIdx.y * 128;
    int j0 = blockIdx.x * 128;
    const HF* Ab = A + (long)b * sA;
    const HF* Bb = B + (long)b * sB;
    int tid = threadIdx.x;
    int lane = tid & 63, w = tid >> 6;
    int wr = w >> 1, wc = w & 1;
    int lr = lane & 15, lk = (lane >> 4) * 8;

    v4f acc[4][4];
    #pragma unroll
    for (int i = 0; i < 4; ++i)
        #pragma unroll
        for (int j = 0; j < 4; ++j) { v4f z = {0.f,0.f,0.f,0.f}; acc[i][j] = z; }

    for (int k0 = 0; k0 < K; k0 += 32) {
        #pragma unroll
        for (int q = 0; q < 2; ++q) {
            int ch = tid*2 + q;          // 0..511
            int row = ch >> 2;
            int c8 = (ch & 3) * 8;
            const uint4* ga = (const uint4*)(Ab + (long)(i0+row)*K + k0 + c8);
            *(uint4*)(&As[row][c8]) = *ga;
            const uint4* gb = (const uint4*)(Bb + (long)(j0+row)*K + k0 + c8);
            *(uint4*)(&Bs[row][c8]) = *gb;
        }
        __syncthreads();
        v8h af[4], bfr[4];
        #pragma unroll
        for (int mf = 0; mf < 4; ++mf)
            af[mf] = *(const v8h*)(&As[wr*64 + mf*16 + lr][lk]);
        #pragma unroll
        for (int nf = 0; nf < 4; ++nf)
            bfr[nf] = *(const v8h*)(&Bs[wc*64 + nf*16 + lr][lk]);
        #pragma unroll
        for (int mf = 0; mf < 4; ++mf)
            #pragma unroll
            for (int nf = 0; nf < 4; ++nf)
                acc[mf][nf] = __builtin_amdgcn_mfma_f32_16x16x32_f16(af[mf], bfr[nf], acc[mf][nf], 0, 0, 0);
        __syncthreads();
    }

    int rbase = (lane >> 4) * 4;
    #pragma unroll
    for (int mf = 0; mf < 4; ++mf) {
        #pragma unroll
        for (int nf = 0; nf < 4; ++nf) {
            #pragma unroll
            for (int r = 0; r < 4; ++r) {
                int row = i0 + wr*64 + mf*16 + rbase + r;
                int col = j0 + wc*64 + nf*16 + lr;
                float v = acc[mf][nf][r];
                if (EPI == 0) {
                    v += bias[row];
                    ((HF*)Cv + (long)b*sC)[(long)row*N + col] = (HF)v;
                } else if (EPI == 3) {
                    v += bias[col];
                    ((HF*)Cv + (long)b*sC)[(long)row*N + col] = (HF)v;
                } else {
                    float* Cf = (float*)Cv + (long)b*sC;
                    const float* Xb = Xres + (long)b*sX;
                    long o = (long)row*N + col;
                    Cf[o] = v * rowScale[row] + rowShift[row] + Xb[o];
                }
            }
        }
    }
}

// ---------------- fused flash attention v9 (c-split, fixed) ----------------
// 512 blocks x 256 thr (4 waves), 2 blocks/CU. batch = bid&7 (XCD-pinned).
// Row-split QK^T+softmax (wave w: rows w*16..w*16+15 of the 64-row block tile);
// c-split PV (wave w: output cols w*64..w*64+63). P values cross waves via
// double-buffered P_buf; alphas cross via double-buffered smem_a[pb][grp][16].
// G fragments in REGISTERS direct from L2 (XCD-pinned), loaded 1 iter ahead;
// arrival guaranteed by the per-iter barrier's vmcnt drain.
// ONE barrier per iter. Safety: PV(t) in [B(t),B(t+1)); softmax(t+2) after B(t+1).
__global__ __launch_bounds__(256, 2) void fused_attn_kernel(
    const HF* __restrict__ TP,   // [B][4096][512], theta = cols 0..255
    const HF* __restrict__ Pt,   // [B][1024][256]
    const HF* __restrict__ G,    // [B][256][1024]
    HF* __restrict__ Yt)         // [B][4096][256]
{
    __shared__ alignas(16) HF P_lds[2][8192];      // [32 kg][32 row][8] k-group-major
    __shared__ alignas(16) HF P_buf[2][4][16][36]; // [pb][rowgrp][row][m], stride 72B
    __shared__ float smem_a[2][4][16];             // [pb][rowgrp][row] alpha
    __shared__ float smem_l[64];                   // final row sums

    int bid = blockIdx.x;
    int b = bid & 7;
    int ntile = bid >> 3;          // 0..63
    int tid = threadIdx.x;
    int lane = tid & 63, w = tid >> 6;
    int lr = lane & 15, lkg = lane >> 4;
    int nbase = ntile * 64;

    const HF* Tq = TP + ((long)b*HW + nbase + w*16) * 512;   // my 16 softmax rows
    const HF* Pb = Pt + (long)b*Mp*CI;
    const HF* Gb = G  + (long)b*CI*Mp + (long)(w*64)*Mp;     // my c-quadrant

    auto stage = [&](int bsel, int m0) {
        #pragma unroll
        for (int q = 0; q < 4; ++q) {
            int idxp = (w*4 + q)*64 + lane;         // 0..1023; dest = idxp*16B
            int pkg = idxp >> 5, prow = idxp & 31;  // [32 kg][32 row][8]
            gload16(Pb + (long)(m0 + prow)*CI + pkg*8, P_lds[bsel] + (size_t)idxp*8);
        }
    };
    auto loadG = [&](int m0, v8h* g) {
        #pragma unroll
        for (int ct = 0; ct < 4; ++ct)
            g[ct] = *(const v8h*)(Gb + (long)(ct*16 + lr)*Mp + m0 + lkg*8);
    };

    // Q fragments in registers for whole kernel (theta cols of TP)
    v8h af[8];
    #pragma unroll
    for (int kf = 0; kf < 8; ++kf)
        af[kf] = *(const v8h*)(Tq + (long)lr*512 + kf*32 + lkg*8);

    v4f acc_y[4][4];   // [row-tile rt][c-tile ct]; Y row = rt*16+lkg*4+r, col = w*64+ct*16+lr
    #pragma unroll
    for (int i = 0; i < 4; ++i)
        #pragma unroll
        for (int j = 0; j < 4; ++j) { v4f z = {0.f,0.f,0.f,0.f}; acc_y[i][j] = z; }
    float mrun[4] = {-1e30f,-1e30f,-1e30f,-1e30f};
    float lsum[4] = {0.f,0.f,0.f,0.f};

    v8h gA[4], gB[4];
    stage(0, 0);
    loadG(0, gA);
    __syncthreads();

    #pragma unroll 2
    for (int t = 0; t < 32; ++t) {
        int cur = t & 1;
        int pb = t & 1;
        v8h* gcur  = (t & 1) ? gB : gA;
        v8h* gnext = (t & 1) ? gA : gB;
        if (t < 31) {
            stage(cur ^ 1, (t+1)*32);     // gload_lds next P chunk
            loadG((t+1)*32, gnext);       // G regs next chunk (issue-early)
        }

        // QK^T: S[my 16 n][32 m]
        v4f acc[2];
        #pragma unroll
        for (int nf = 0; nf < 2; ++nf) { v4f z = {0.f,0.f,0.f,0.f}; acc[nf] = z; }
        __builtin_amdgcn_s_setprio(1);
        #pragma unroll
        for (int kf = 0; kf < 8; ++kf) {
            #pragma unroll
            for (int nf = 0; nf < 2; ++nf) {
                v8h bfr = *(const v8h*)(P_lds[cur] + (kf*4 + lkg)*256 + (nf*16 + lr)*8);
                acc[nf] = __builtin_amdgcn_mfma_f32_16x16x32_f16(af[kf], bfr, acc[nf], 0, 0, 0);
            }
        }
        __builtin_amdgcn_s_setprio(0);

        // online softmax for my 16 rows; alpha broadcast via smem_a[pb]
        #pragma unroll
        for (int r = 0; r < 4; ++r) {
            float cm = fmaxf(acc[0][r], acc[1][r]);
            #pragma unroll
            for (int d = 1; d < 16; d <<= 1) cm = fmaxf(cm, __shfl_xor(cm, d));
            float alpha = 1.f;
            if (cm > mrun[r]) {                   // uniform across the row's 16 lanes
                alpha = __expf(mrun[r] - cm);     // first iter: exp(-inf)=0 zeroes empty acc
                mrun[r] = cm;
                lsum[r] *= alpha;
            }
            int row = lkg*4 + r;
            if (lr == 0) smem_a[pb][w][row] = alpha;   // lanes 0/16/32/48: disjoint rows
            #pragma unroll
            for (int nf = 0; nf < 2; ++nf) {
                float p = __expf(acc[nf][r] - mrun[r]);   // <= 1
                lsum[r] += p;
                P_buf[pb][w][row][nf*16 + lr] = (HF)p;
            }
        }

        __syncthreads();   // P_buf[pb]+smem_a[pb] visible; vmcnt drained (P_lds + G regs)

        // PV: Y[64 n][my 64 c] += P(64x32) @ G^T (G in registers)
        __builtin_amdgcn_s_setprio(1);
        #pragma unroll
        for (int rt = 0; rt < 4; ++rt) {
            v8h ap;
            {
                v4h a0 = *(const v4h*)(&P_buf[pb][rt][lr][lkg*8]);
                v4h a1 = *(const v4h*)(&P_buf[pb][rt][lr][lkg*8 + 4]);
                ap = __builtin_shufflevector(a0, a1, 0,1,2,3,4,5,6,7);
            }
            float al0 = smem_a[pb][rt][lkg*4 + 0];
            float al1 = smem_a[pb][rt][lkg*4 + 1];
            float al2 = smem_a[pb][rt][lkg*4 + 2];
            float al3 = smem_a[pb][rt][lkg*4 + 3];
            #pragma unroll
            for (int ct = 0; ct < 4; ++ct) {
                acc_y[rt][ct][0] *= al0;
                acc_y[rt][ct][1] *= al1;
                acc_y[rt][ct][2] *= al2;
                acc_y[rt][ct][3] *= al3;
                acc_y[rt][ct] = __builtin_amdgcn_mfma_f32_16x16x32_f16(ap, gcur[ct], acc_y[rt][ct], 0, 0, 0);
            }
        }
        __builtin_amdgcn_s_setprio(0);
    }

    // epilogue: publish row sums, then Y /= l, write f16
    #pragma unroll
    for (int r = 0; r < 4; ++r) {
        float s = lsum[r];
        #pragma unroll
        for (int d = 1; d < 16; d <<= 1) s += __shfl_xor(s, d);
        if (lr == 0) smem_l[w*16 + lkg*4 + r] = s;
    }
    __syncthreads();
    HF* Yb = Yt + ((long)b*HW + nbase) * CI;
    #pragma unroll
    for (int rt = 0; rt < 4; ++rt) {
        #pragma unroll
        for (int r = 0; r < 4; ++r) {
            int row = rt*16 + lkg*4 + r;
            float inv = 1.f / smem_l[row];
            #pragma unroll
            for (int ct = 0; ct < 4; ++ct)
                Yb[(long)row*CI + w*64 + ct*16 + lr] = (HF)(acc_y[rt][ct][r] * inv);
        }
    }
}

extern "C" void kernel_launch(void* const* d_in, const int* in_sizes, int n_in,
                              void* d_out, int out_size, void* d_ws, size_t ws_size,
                              hipStream_t stream)
{
    const float* x     = (const float*)d_in[0];
    const float* w_g   = (const float*)d_in[1];
    const float* b_g   = (const float*)d_in[2];
    const float* w_th  = (const float*)d_in[3];
    const float* b_th  = (const float*)d_in[4];
    const float* w_ph  = (const float*)d_in[5];
    const float* b_ph  = (const float*)d_in[6];
    const float* w_out = (const float*)d_in[7];
    const float* b_out = (const float*)d_in[8];
    const float* gamma = (const float*)d_in[9];
    const float* beta  = (const float*)d_in[10];
    const float* mean  = (const float*)d_in[11];
    const float* var   = (const float*)d_in[12];
    float* out = (float*)d_out;

    char* ws = (char*)d_ws;
    size_t off = 0;
    auto alloc = [&](size_t bytes) { void* p = ws + off; off += (bytes + 255) & ~(size_t)255; return p; };
    HF*    wall  = (HF*)alloc((size_t)768*512*2);   // rows: theta 0-255, phi 256-511, g 512-767
    float* ball  = (float*)alloc(768*4);
    HF*    wo    = (HF*)alloc((size_t)512*256*2);
    float* scale = (float*)alloc(512*4);
    float* shift = (float*)alloc(512*4);
    HF*    xT    = (HF*)alloc((size_t)Bn*HW*Cc*2);
    HF*    TP    = (HF*)alloc((size_t)Bn*HW*512*2);  // [s][theta|phi]
    HF*    Gg    = (HF*)alloc((size_t)Bn*CI*HW*2);   // g conv, c-major
    HF*    Pt    = (HF*)alloc((size_t)Bn*Mp*CI*2);
    HF*    G     = (HF*)alloc((size_t)Bn*CI*Mp*2);
    HF*    Yt    = (HF*)alloc((size_t)Bn*HW*CI*2);

    prep_kernel<<<1536, 256, 0, stream>>>(w_g,b_g,w_th,b_th,w_ph,b_ph,w_out,b_out,gamma,beta,mean,var,
                                          wall, ball, wo, scale, shift);
    transpose_x_kernel<<<dim3(64,8,Bn), 256, 0, stream>>>(x, xT);
    // TP[b, s, o] = xT @ {w_th|w_ph}^T + colBias
    gemm_bt_kernel<3><<<dim3(4,32,Bn), 256, 0, stream>>>(xT, (long)HW*Cc, wall, 0, TP, (long)HW*512,
                                                         HW, 512, Cc, ball, nullptr, nullptr, nullptr, 0);
    // Gg[b, c, s] = w_g @ xT^T + rowBias
    gemm_bt_kernel<0><<<dim3(32,2,Bn), 256, 0, stream>>>(wall + (size_t)512*512, 0, xT, (long)HW*Cc,
                                                         Gg, (long)CI*HW, CI, HW, Cc, ball + 512,
                                                         nullptr, nullptr, nullptr, 0);
    // phi -> pooled Pt[b, m, c]
    pool_sm_kernel<<<1024, 256, 0, stream>>>(TP, Pt);
    // g -> pooled G[b, c, m]
    pool_kernel<<<8192, 256, 0, stream>>>(Gg, (long)CI*HW, G, (long)CI*Mp);
    // fused scores+softmax+PV -> Yt[b, n, c]
    fused_attn_kernel<<<512, 256, 0, stream>>>(TP, Pt, G, Yt);
    // out[b, co, n] = wo @ Yt^T * scale + shift + x
    gemm_bt_kernel<2><<<dim3(32,4,Bn), 256, 0, stream>>>(wo, 0, Yt, (long)HW*CI, out, (long)Cc*HW,
                                                         Cc, HW, CI, nullptr, scale, shift, x, (long)Cc*HW);
}

// Round 12
// 201.073 us; speedup vs baseline: 1.6097x; 1.0247x over previous
//
#include <hip/hip_runtime.h>

typedef _Float16 v8h __attribute__((ext_vector_type(8)));
typedef _Float16 v4h __attribute__((ext_vector_type(4)));
typedef float v4f __attribute__((ext_vector_type(4)));
#define HF _Float16

// dims
#define Bn 8
#define Cc 512
#define CI 256
#define HW 4096   // 64*64
#define Mp 1024   // 32*32 pooled

__device__ __forceinline__ void gload16(const void* g, void* l) {
    __builtin_amdgcn_global_load_lds((const __attribute__((address_space(1))) void*)g,
                                     (__attribute__((address_space(3))) void*)l, 16, 0, 0);
}

// ---------------- prep: weights fp32->f16, BN fold ----------------
__global__ __launch_bounds__(256) void prep_kernel(
    const float* __restrict__ w_g, const float* __restrict__ b_g,
    const float* __restrict__ w_th, const float* __restrict__ b_th,
    const float* __restrict__ w_ph, const float* __restrict__ b_ph,
    const float* __restrict__ w_out, const float* __restrict__ b_out,
    const float* __restrict__ gamma, const float* __restrict__ beta,
    const float* __restrict__ mean, const float* __restrict__ var,
    HF* __restrict__ wall, float* __restrict__ ball,
    HF* __restrict__ wo, float* __restrict__ scale, float* __restrict__ shift)
{
    int idx = blockIdx.x * 256 + threadIdx.x;
    if (idx < 768*512) {
        int o = idx >> 9;
        float v = (o < 256) ? w_th[idx] : (o < 512) ? w_ph[idx - 256*512] : w_g[idx - 512*512];
        wall[idx] = (HF)v;
    }
    if (idx < 512*256) wo[idx] = (HF)w_out[idx];
    if (idx < 768) ball[idx] = (idx < 256) ? b_th[idx] : (idx < 512) ? b_ph[idx-256] : b_g[idx-512];
    if (idx < 512) {
        float inv = gamma[idx] * rsqrtf(var[idx] + 1e-5f);
        scale[idx] = inv;
        shift[idx] = (b_out[idx] - mean[idx]) * inv + beta[idx];
    }
}

// ---------------- transpose x: (b,c,s) fp32 -> xT (b,s,c) f16 ----------------
__global__ __launch_bounds__(256) void transpose_x_kernel(const float* __restrict__ x, HF* __restrict__ xT)
{
    __shared__ float tile[64][65];
    int b = blockIdx.z;
    int c0 = blockIdx.y * 64, s0 = blockIdx.x * 64;
    int tr = threadIdx.x >> 6, ts = threadIdx.x & 63;
    #pragma unroll
    for (int i = 0; i < 16; ++i) {
        int r = tr + i*4;
        tile[r][ts] = x[((long)(b*Cc) + c0 + r)*HW + s0 + ts];
    }
    __syncthreads();
    #pragma unroll
    for (int i = 0; i < 16; ++i) {
        int r = tr + i*4;
        xT[((long)b*HW + s0 + r)*Cc + c0 + ts] = (HF)tile[ts][r];
    }
}

// ---------------- 2x2 maxpool from s-major phi: Ph[s, c] -> Pt[m, c] ----------------
__global__ __launch_bounds__(256) void pool_sm_kernel(const HF* __restrict__ TP, HF* __restrict__ Pt)
{
    int idx = blockIdx.x * 256 + threadIdx.x;   // Bn*1024*32
    int c8 = idx & 31;
    int m  = (idx >> 5) & 1023;
    int b  = idx >> 15;
    int h2 = m >> 5, w2 = m & 31;
    int s00 = h2*128 + w2*2;
    const HF* base = TP + ((long)b*HW + s00)*512 + 256 + c8*8;
    v8h a0 = *(const v8h*)(base);
    v8h a1 = *(const v8h*)(base + 512);
    v8h a2 = *(const v8h*)(base + 64*512);
    v8h a3 = *(const v8h*)(base + 65*512);
    v8h o;
    #pragma unroll
    for (int j = 0; j < 8; ++j) {
        float v = fmaxf(fmaxf((float)a0[j], (float)a1[j]), fmaxf((float)a2[j], (float)a3[j]));
        o[j] = (HF)v;
    }
    *(v8h*)(Pt + ((long)b*Mp + m)*CI + c8*8) = o;
}

// ---------------- 2x2 maxpool c-major: Gg (b,c,64,64) -> G (b,c,32,32) ----------------
__global__ __launch_bounds__(256) void pool_kernel(const HF* __restrict__ src, long sSrc,
                                                   HF* __restrict__ dst, long sDst)
{
    long idx = (long)blockIdx.x * 256 + threadIdx.x;   // Bn*256*1024
    int m = idx & 1023;
    long bc = idx >> 10;
    int c = (int)(bc & 255);
    int b = (int)(bc >> 8);
    int h2 = m >> 5, w2 = m & 31;
    const HF* p = src + (long)b*sSrc + (long)c*HW + h2*128 + w2*2;
    float v = fmaxf(fmaxf((float)p[0], (float)p[1]), fmaxf((float)p[64], (float)p[65]));
    dst[(long)b*sDst + (long)c*Mp + m] = (HF)v;
}

// ---------------- generic tiled gemm_bt: C[i,j] = sum_k A[i,k]*B[j,k] ----------------
// reg-staged, [128][40] padded LDS, 2 barriers/step (measured fastest here).
template<int EPI>
__global__ __launch_bounds__(256) void gemm_bt_kernel(
    const HF* __restrict__ A, long sA, const HF* __restrict__ B, long sB,
    void* __restrict__ Cv, long sC, int M, int N, int K,
    const float* __restrict__ bias,
    const float* __restrict__ rowScale, const float* __restrict__ rowShift,
    const float* __restrict__ Xres, long sX)
{
    __shared__ HF As[128][40];
    __shared__ HF Bs[128][40];
    int b = blockIdx.z;
    int i0 = blockIdx.y * 128;
    int j0 = blockIdx.x * 128;
    const HF* Ab = A + (long)b * sA;
    const HF* Bb = B + (long)b * sB;
    int tid = threadIdx.x;
    int lane = tid & 63, w = tid >> 6;
    int wr = w >> 1, wc = w & 1;
    int lr = lane & 15, lk = (lane >> 4) * 8;

    v4f acc[4][4];
    #pragma unroll
    for (int i = 0; i < 4; ++i)
        #pragma unroll
        for (int j = 0; j < 4; ++j) { v4f z = {0.f,0.f,0.f,0.f}; acc[i][j] = z; }

    for (int k0 = 0; k0 < K; k0 += 32) {
        #pragma unroll
        for (int q = 0; q < 2; ++q) {
            int ch = tid*2 + q;          // 0..511
            int row = ch >> 2;
            int c8 = (ch & 3) * 8;
            const uint4* ga = (const uint4*)(Ab + (long)(i0+row)*K + k0 + c8);
            *(uint4*)(&As[row][c8]) = *ga;
            const uint4* gb = (const uint4*)(Bb + (long)(j0+row)*K + k0 + c8);
            *(uint4*)(&Bs[row][c8]) = *gb;
        }
        __syncthreads();
        v8h af[4], bfr[4];
        #pragma unroll
        for (int mf = 0; mf < 4; ++mf)
            af[mf] = *(const v8h*)(&As[wr*64 + mf*16 + lr][lk]);
        #pragma unroll
        for (int nf = 0; nf < 4; ++nf)
            bfr[nf] = *(const v8h*)(&Bs[wc*64 + nf*16 + lr][lk]);
        #pragma unroll
        for (int mf = 0; mf < 4; ++mf)
            #pragma unroll
            for (int nf = 0; nf < 4; ++nf)
                acc[mf][nf] = __builtin_amdgcn_mfma_f32_16x16x32_f16(af[mf], bfr[nf], acc[mf][nf], 0, 0, 0);
        __syncthreads();
    }

    int rbase = (lane >> 4) * 4;
    #pragma unroll
    for (int mf = 0; mf < 4; ++mf) {
        #pragma unroll
        for (int nf = 0; nf < 4; ++nf) {
            #pragma unroll
            for (int r = 0; r < 4; ++r) {
                int row = i0 + wr*64 + mf*16 + rbase + r;
                int col = j0 + wc*64 + nf*16 + lr;
                float v = acc[mf][nf][r];
                if (EPI == 0) {
                    v += bias[row];
                    ((HF*)Cv + (long)b*sC)[(long)row*N + col] = (HF)v;
                } else if (EPI == 3) {
                    v += bias[col];
                    ((HF*)Cv + (long)b*sC)[(long)row*N + col] = (HF)v;
                } else {
                    float* Cf = (float*)Cv + (long)b*sC;
                    const float* Xb = Xres + (long)b*sX;
                    long o = (long)row*N + col;
                    Cf[o] = v * rowScale[row] + rowShift[row] + Xb[o];
                }
            }
        }
    }
}

// ---------------- fused flash attention v10 (swapped QK^T + defer-rescale) ----------------
// 512 blocks x 256 thr (4 waves), 2 blocks/CU. batch = bid&7 (XCD-pinned).
// SWAPPED QK^T: S^T = mfma(P_frag, T_frag) -> lane holds S for ONE n-row (n=lr),
// 8 m-contiguous values. Row-max = 7 in-lane max + 2 shuffles; mrun/lsum scalar;
// P packs as 2 x b64 LDS writes (vs 32 scalars). Defer-rescale THR=7: alpha==1
// almost every iter -> PV skips the 64 acc_y mults via __any.
// c-split PV (wave w: cols w*64..); G regs direct from L2, loaded 1 iter ahead.
__global__ __launch_bounds__(256, 2) void fused_attn_kernel(
    const HF* __restrict__ TP,   // [B][4096][512], theta = cols 0..255
    const HF* __restrict__ Pt,   // [B][1024][256]
    const HF* __restrict__ G,    // [B][256][1024]
    HF* __restrict__ Yt)         // [B][4096][256]
{
    __shared__ alignas(16) HF P_lds[2][8192];      // [32 kg][32 row][8] k-group-major
    __shared__ alignas(16) HF P_buf[2][4][16][36]; // [pb][rowgrp][n 16][m 32+4pad]
    __shared__ alignas(16) float smem_a[2][4][16]; // [pb][rowgrp][n] alpha
    __shared__ float smem_l[64];                   // final row sums

    int bid = blockIdx.x;
    int b = bid & 7;
    int ntile = bid >> 3;          // 0..63
    int tid = threadIdx.x;
    int lane = tid & 63, w = tid >> 6;
    int lr = lane & 15, lkg = lane >> 4;
    int nbase = ntile * 64;

    const HF* Tq = TP + ((long)b*HW + nbase + w*16) * 512;   // my 16 softmax rows
    const HF* Pb = Pt + (long)b*Mp*CI;
    const HF* Gb = G  + (long)b*CI*Mp + (long)(w*64)*Mp;     // my c-quadrant

    auto stage = [&](int bsel, int m0) {
        #pragma unroll
        for (int q = 0; q < 4; ++q) {
            int idxp = (w*4 + q)*64 + lane;         // 0..1023; dest = idxp*16B
            int pkg = idxp >> 5, prow = idxp & 31;  // [32 kg][32 row][8]
            gload16(Pb + (long)(m0 + prow)*CI + pkg*8, P_lds[bsel] + (size_t)idxp*8);
        }
    };
    auto loadG = [&](int m0, v8h* g) {
        #pragma unroll
        for (int ct = 0; ct < 4; ++ct)
            g[ct] = *(const v8h*)(Gb + (long)(ct*16 + lr)*Mp + m0 + lkg*8);
    };

    // Q fragments in registers for whole kernel (theta cols of TP)
    v8h af[8];
    #pragma unroll
    for (int kf = 0; kf < 8; ++kf)
        af[kf] = *(const v8h*)(Tq + (long)lr*512 + kf*32 + lkg*8);

    v4f acc_y[4][4];   // [row-tile rt][c-tile ct]; Y row = rt*16+lkg*4+r, col = w*64+ct*16+lr
    #pragma unroll
    for (int i = 0; i < 4; ++i)
        #pragma unroll
        for (int j = 0; j < 4; ++j) { v4f z = {0.f,0.f,0.f,0.f}; acc_y[i][j] = z; }
    float mrun = -1e30f;   // running max for my row n = nbase + w*16 + lr
    float lsum = 0.f;      // per-lane partial sum over my m's

    v8h gA[4], gB[4];
    stage(0, 0);
    loadG(0, gA);
    __syncthreads();

    for (int t = 0; t < 32; ++t) {
        int cur = t & 1;
        int pb = t & 1;
        v8h* gcur  = (t & 1) ? gB : gA;
        v8h* gnext = (t & 1) ? gA : gB;
        if (t < 31) {
            stage(cur ^ 1, (t+1)*32);     // gload_lds next P chunk
            loadG((t+1)*32, gnext);       // G regs next chunk (issue-early)
        }

        // QK^T swapped: acc[mt] holds S[n=lr][m = mt*16 + lkg*4 + r]
        v4f acc[2];
        #pragma unroll
        for (int mt = 0; mt < 2; ++mt) { v4f z = {0.f,0.f,0.f,0.f}; acc[mt] = z; }
        __builtin_amdgcn_s_setprio(1);
        #pragma unroll
        for (int kf = 0; kf < 8; ++kf) {
            #pragma unroll
            for (int mt = 0; mt < 2; ++mt) {
                v8h pf = *(const v8h*)(P_lds[cur] + (kf*4 + lkg)*256 + (mt*16 + lr)*8);
                acc[mt] = __builtin_amdgcn_mfma_f32_16x16x32_f16(pf, af[kf], acc[mt], 0, 0, 0);
            }
        }
        __builtin_amdgcn_s_setprio(0);

        // softmax: per-lane row n=lr. 7 in-lane max + 2 shuffles.
        float cm = fmaxf(fmaxf(fmaxf(acc[0][0], acc[0][1]), fmaxf(acc[0][2], acc[0][3])),
                         fmaxf(fmaxf(acc[1][0], acc[1][1]), fmaxf(acc[1][2], acc[1][3])));
        cm = fmaxf(cm, __shfl_xor(cm, 16));
        cm = fmaxf(cm, __shfl_xor(cm, 32));
        float alpha = 1.f;
        if (cm > mrun + 7.f) {            // defer: p <= e^7 = 1096, f16-safe
            alpha = __expf(mrun - cm);    // first iter: exp(-inf)=0 zeroes empty acc
            mrun = cm;
            lsum *= alpha;
        }
        if (lane < 16) smem_a[pb][w][lr] = alpha;
        #pragma unroll
        for (int mt = 0; mt < 2; ++mt) {
            v4h p4;
            #pragma unroll
            for (int r = 0; r < 4; ++r) {
                float p = __expf(acc[mt][r] - mrun);
                lsum += p;
                p4[r] = (HF)p;
            }
            *(v4h*)(&P_buf[pb][w][lr][mt*16 + lkg*4]) = p4;   // one b64 per mt
        }

        __syncthreads();   // P_buf[pb]+smem_a[pb] visible; vmcnt drained (P_lds + G regs)

        // PV: Y[64 n][my 64 c] += P(64x32) @ G^T (G in registers)
        __builtin_amdgcn_s_setprio(1);
        v4f alv[4];
        bool need = false;
        #pragma unroll
        for (int rt = 0; rt < 4; ++rt) {
            alv[rt] = *(const v4f*)(&smem_a[pb][rt][lkg*4]);
            need = need | (alv[rt][0] != 1.f) | (alv[rt][1] != 1.f)
                        | (alv[rt][2] != 1.f) | (alv[rt][3] != 1.f);
        }
        if (__any(need)) {
            #pragma unroll
            for (int rt = 0; rt < 4; ++rt)
                #pragma unroll
                for (int ct = 0; ct < 4; ++ct)
                    #pragma unroll
                    for (int r = 0; r < 4; ++r)
                        acc_y[rt][ct][r] *= alv[rt][r];
        }
        #pragma unroll
        for (int rt = 0; rt < 4; ++rt) {
            v8h ap;
            {
                v4h a0 = *(const v4h*)(&P_buf[pb][rt][lr][lkg*8]);
                v4h a1 = *(const v4h*)(&P_buf[pb][rt][lr][lkg*8 + 4]);
                ap = __builtin_shufflevector(a0, a1, 0,1,2,3,4,5,6,7);
            }
            #pragma unroll
            for (int ct = 0; ct < 4; ++ct)
                acc_y[rt][ct] = __builtin_amdgcn_mfma_f32_16x16x32_f16(ap, gcur[ct], acc_y[rt][ct], 0, 0, 0);
        }
        __builtin_amdgcn_s_setprio(0);
    }

    // epilogue: total row sums (2 shuffles), publish, then Y /= l, write f16
    lsum += __shfl_xor(lsum, 16);
    lsum += __shfl_xor(lsum, 32);
    if (lane < 16) smem_l[w*16 + lr] = lsum;
    __syncthreads();
    HF* Yb = Yt + ((long)b*HW + nbase) * CI;
    #pragma unroll
    for (int rt = 0; rt < 4; ++rt) {
        #pragma unroll
        for (int r = 0; r < 4; ++r) {
            int row = rt*16 + lkg*4 + r;
            float inv = 1.f / smem_l[row];
            #pragma unroll
            for (int ct = 0; ct < 4; ++ct)
                Yb[(long)row*CI + w*64 + ct*16 + lr] = (HF)(acc_y[rt][ct][r] * inv);
        }
    }
}

extern "C" void kernel_launch(void* const* d_in, const int* in_sizes, int n_in,
                              void* d_out, int out_size, void* d_ws, size_t ws_size,
                              hipStream_t stream)
{
    const float* x     = (const float*)d_in[0];
    const float* w_g   = (const float*)d_in[1];
    const float* b_g   = (const float*)d_in[2];
    const float* w_th  = (const float*)d_in[3];
    const float* b_th  = (const float*)d_in[4];
    const float* w_ph  = (const float*)d_in[5];
    const float* b_ph  = (const float*)d_in[6];
    const float* w_out = (const float*)d_in[7];
    const float* b_out = (const float*)d_in[8];
    const float* gamma = (const float*)d_in[9];
    const float* beta  = (const float*)d_in[10];
    const float* mean  = (const float*)d_in[11];
    const float* var   = (const float*)d_in[12];
    float* out = (float*)d_out;

    char* ws = (char*)d_ws;
    size_t off = 0;
    auto alloc = [&](size_t bytes) { void* p = ws + off; off += (bytes + 255) & ~(size_t)255; return p; };
    HF*    wall  = (HF*)alloc((size_t)768*512*2);   // rows: theta 0-255, phi 256-511, g 512-767
    float* ball  = (float*)alloc(768*4);
    HF*    wo    = (HF*)alloc((size_t)512*256*2);
    float* scale = (float*)alloc(512*4);
    float* shift = (float*)alloc(512*4);
    HF*    xT    = (HF*)alloc((size_t)Bn*HW*Cc*2);
    HF*    TP    = (HF*)alloc((size_t)Bn*HW*512*2);  // [s][theta|phi]
    HF*    Gg    = (HF*)alloc((size_t)Bn*CI*HW*2);   // g conv, c-major
    HF*    Pt    = (HF*)alloc((size_t)Bn*Mp*CI*2);
    HF*    G     = (HF*)alloc((size_t)Bn*CI*Mp*2);
    HF*    Yt    = (HF*)alloc((size_t)Bn*HW*CI*2);

    prep_kernel<<<1536, 256, 0, stream>>>(w_g,b_g,w_th,b_th,w_ph,b_ph,w_out,b_out,gamma,beta,mean,var,
                                          wall, ball, wo, scale, shift);
    transpose_x_kernel<<<dim3(64,8,Bn), 256, 0, stream>>>(x, xT);
    // TP[b, s, o] = xT @ {w_th|w_ph}^T + colBias
    gemm_bt_kernel<3><<<dim3(4,32,Bn), 256, 0, stream>>>(xT, (long)HW*Cc, wall, 0, TP, (long)HW*512,
                                                         HW, 512, Cc, ball, nullptr, nullptr, nullptr, 0);
    // Gg[b, c, s] = w_g @ xT^T + rowBias
    gemm_bt_kernel<0><<<dim3(32,2,Bn), 256, 0, stream>>>(wall + (size_t)512*512, 0, xT, (long)HW*Cc,
                                                         Gg, (long)CI*HW, CI, HW, Cc, ball + 512,
                                                         nullptr, nullptr, nullptr, 0);
    // phi -> pooled Pt[b, m, c]
    pool_sm_kernel<<<1024, 256, 0, stream>>>(TP, Pt);
    // g -> pooled G[b, c, m]
    pool_kernel<<<8192, 256, 0, stream>>>(Gg, (long)CI*HW, G, (long)CI*Mp);
    // fused scores+softmax+PV -> Yt[b, n, c]
    fused_attn_kernel<<<512, 256, 0, stream>>>(TP, Pt, G, Yt);
    // out[b, co, n] = wo @ Yt^T * scale + shift + x
    gemm_bt_kernel<2><<<dim3(32,4,Bn), 256, 0, stream>>>(wo, 0, Yt, (long)HW*CI, out, (long)Cc*HW,
                                                         Cc, HW, CI, nullptr, scale, shift, x, (long)Cc*HW);
}